// Round 18
// baseline (491.502 us; speedup 1.0000x reference)
//
#include <hip/hip_runtime.h>
#include <stdint.h>

typedef unsigned short u16;
typedef short bf16x8 __attribute__((ext_vector_type(8)));
typedef float f32x4 __attribute__((ext_vector_type(4)));

#define NTOK 100352      // B*H*W tokens
#define NWIN 2048        // B * 64 windows
#define CC 256
#define NHEAD 8
#define HDIM 32
#define NWT 49           // tokens per window
#define MLPD 1024
#define ATT_SCALE 0.17677669529663687f  // 32^-0.5

__device__ __forceinline__ u16 f2b(float f) {
  union { float f; uint32_t u; } c; c.f = f;
  return (u16)((c.u + 0x7fffu + ((c.u >> 16) & 1u)) >> 16);
}
__device__ __forceinline__ float b2f(u16 h) {
  union { uint32_t u; float f; } c; c.u = ((uint32_t)h) << 16;
  return c.f;
}
// packed f32x2 -> bf16x2 (RNE), 1 VALU op
__device__ __forceinline__ uint32_t f2b2(float lo, float hi) {
  uint32_t r;
  asm("v_cvt_pk_bf16_f32 %0, %1, %2" : "=v"(r) : "v"(lo), "v"(hi));
  return r;
}

__device__ __forceinline__ void gload_lds16(const void* g, void* l) {
  __builtin_amdgcn_global_load_lds((const __attribute__((address_space(1))) void*)g,
                                   (__attribute__((address_space(3))) void*)l, 16, 0, 0);
}

// ---------------- prep: all weight transposes + bias LUT in ONE dispatch
__global__ __launch_bounds__(256)
void prep_k(const float* __restrict__ wqkv, const float* __restrict__ wproj,
            const float* __restrict__ wfc1, const float* __restrict__ wfc2,
            const float* __restrict__ rpb,
            u16* __restrict__ qkvT, u16* __restrict__ projT,
            u16* __restrict__ fc1T, u16* __restrict__ fc2T, float* __restrict__ lut) {
  int i = blockIdx.x * 256 + threadIdx.x;
  if (i < 196608) {                     // wqkv: K=256, N=768
    int k = i / 768, n = i % 768;
    qkvT[(size_t)n * 256 + k] = f2b(wqkv[i]);
  } else if (i < 262144) {              // wproj: 256x256
    int j = i - 196608, k = j / 256, n = j % 256;
    projT[(size_t)n * 256 + k] = f2b(wproj[j]);
  } else if (i < 524288) {              // wfc1: K=256, N=1024
    int j = i - 262144, k = j / 1024, n = j % 1024;
    fc1T[(size_t)n * 256 + k] = f2b(wfc1[j]);
  } else if (i < 786432) {              // wfc2: K=1024, N=256
    int j = i - 524288, k = j / 256, n = j % 256;
    fc2T[(size_t)n * 1024 + k] = f2b(wfc2[j]);
  } else if (i < 819200) {              // bias LUT lut[h][m][n], 64x64 padded
    int j = i - 786432;
    int h = j >> 12, m = (j >> 6) & 63, n = j & 63;
    float v = 0.f;
    if (m < 49 && n < 49) {
      int i1 = n / 7, j1 = n % 7, i2 = m / 7, j2 = m % 7;
      v = rpb[((i1 - i2 + 6) * 13 + (j1 - j2 + 6)) * 8 + h];
    }
    lut[j] = v;
  }
}

// ---------------- LN1 + cyclic-shift + window-partition -> bf16 tokens
__global__ __launch_bounds__(256)
void ln_k(const float* __restrict__ x, const float* __restrict__ g,
          const float* __restrict__ be, u16* __restrict__ out) {
  int token = blockIdx.x * 4 + (threadIdx.x >> 6);
  int lane = threadIdx.x & 63;
  int win = token / 49, nn = token % 49;
  int b = win >> 6, wh = (win >> 3) & 7, ww = win & 7;
  int i = nn / 7, j = nn % 7;
  int h = wh * 7 + i + 3; if (h >= 56) h -= 56;
  int w = ww * 7 + j + 3; if (w >= 56) w -= 56;
  size_t src = ((size_t)((b * 56 + h) * 56 + w)) * CC;
  f32x4 v = *(const f32x4*)&x[src + lane * 4];
  float s1 = v[0] + v[1] + v[2] + v[3];
  float s2 = v[0]*v[0] + v[1]*v[1] + v[2]*v[2] + v[3]*v[3];
#pragma unroll
  for (int o = 32; o; o >>= 1) { s1 += __shfl_xor(s1, o); s2 += __shfl_xor(s2, o); }
  float mean = s1 * (1.f / 256.f);
  float var = s2 * (1.f / 256.f) - mean * mean;
  float rstd = rsqrtf(var + 1e-5f);
  f32x4 gv = *(const f32x4*)&g[lane * 4];
  f32x4 bv = *(const f32x4*)&be[lane * 4];
  float y0 = (v[0]-mean)*rstd*gv[0] + bv[0];
  float y1 = (v[1]-mean)*rstd*gv[1] + bv[1];
  float y2 = (v[2]-mean)*rstd*gv[2] + bv[2];
  float y3 = (v[3]-mean)*rstd*gv[3] + bv[3];
  *(uint2*)&out[(size_t)token * CC + lane * 4] = make_uint2(f2b2(y0, y1), f2b2(y2, y3));
}

// ---------------- GEMM (128x128, BK=64): A dbuf (32KB) + B single-buffer (16KB)
#define BM 128
#define BN 128
enum { EPI_QKV = 0 };

template<int EPI, int NKT>
__global__ __launch_bounds__(256)
void gemm_k(const u16* __restrict__ A, const u16* __restrict__ BT,
            const float* __restrict__ bias,
            void* __restrict__ p0, const void* __restrict__ p1) {
  constexpr int K = NKT * 64;
  __shared__ u16 aL[2][BM * 64];   // 32KB double-buffered
  __shared__ u16 bL[BN * 64];      // 16KB single (staged 1 tile ahead)
  const int tid = threadIdx.x;
  const int lane = tid & 63;
  const int wv = tid >> 6;
  const int wm = wv >> 1, wn = wv & 1;

  int bx = blockIdx.x, by = blockIdx.y;
  {
    int nwg = gridDim.x * gridDim.y;
    int lin = by * gridDim.x + bx;
    int q = nwg >> 3, r = nwg & 7;
    int xcd = lin & 7, idx = lin >> 3;
    int wg = (xcd < r ? xcd * (q + 1) : r * (q + 1) + (xcd - r) * q) + idx;
    bx = wg % gridDim.x;
    by = wg / gridDim.x;
  }
  const long m0 = (long)by * BM;
  const int n0 = bx * BN;

  f32x4 acc[4][4] = {};   // [n-tile][m-tile]
  const int r15 = lane & 15;
  const int g4 = lane >> 4;

  const u16* pA[4];
  const u16* pB[4];
  int lslot[4];
#pragma unroll
  for (int it = 0; it < 4; ++it) {
    int slot = tid + 256 * it;
    int row = slot >> 3, c8 = slot & 7;
    int cs = c8 ^ (row & 7);
    pA[it] = &A[(m0 + row) * K + cs * 8];
    pB[it] = &BT[(size_t)(n0 + row) * K + cs * 8];
    lslot[it] = slot * 8;
  }
  int aoff[2][4], boff[2][4];
#pragma unroll
  for (int kk = 0; kk < 2; ++kk)
#pragma unroll
    for (int m = 0; m < 4; ++m) {
      int rowa = wm * 64 + m * 16 + r15;
      aoff[kk][m] = rowa * 64 + (((kk * 4 + g4) ^ (rowa & 7)) << 3);
      int rowb = wn * 64 + m * 16 + r15;
      boff[kk][m] = rowb * 64 + (((kk * 4 + g4) ^ (rowb & 7)) << 3);
    }

  auto stageA = [&](int bufi) {
#pragma unroll
    for (int it = 0; it < 4; ++it) { gload_lds16(pA[it], &aL[bufi][lslot[it]]); pA[it] += 64; }
  };
  auto stageB = [&]() {
#pragma unroll
    for (int it = 0; it < 4; ++it) { gload_lds16(pB[it], &bL[lslot[it]]); pB[it] += 64; }
  };

  stageB();
  stageA(0);
  stageA(1);

  for (int t = 0; t < NKT; ++t) {
    if (t + 1 < NKT) asm volatile("s_waitcnt vmcnt(4)" ::: "memory");
    else             asm volatile("s_waitcnt vmcnt(0)" ::: "memory");
    __builtin_amdgcn_sched_barrier(0);
    __builtin_amdgcn_s_barrier();
    __builtin_amdgcn_sched_barrier(0);
    {
      const u16* ab = aL[t & 1];
#pragma unroll
      for (int kk = 0; kk < 2; ++kk) {
        bf16x8 af[4], bfr[4];
#pragma unroll
        for (int m = 0; m < 4; ++m) af[m] = *(const bf16x8*)&ab[aoff[kk][m]];
#pragma unroll
        for (int n = 0; n < 4; ++n) bfr[n] = *(const bf16x8*)&bL[boff[kk][n]];
#pragma unroll
        for (int n = 0; n < 4; ++n)
#pragma unroll
          for (int m = 0; m < 4; ++m)
            acc[n][m] = __builtin_amdgcn_mfma_f32_16x16x32_bf16(bfr[n], af[m], acc[n][m], 0, 0, 0);
      }
    }
    __builtin_amdgcn_sched_barrier(0);
    __builtin_amdgcn_s_barrier();
    __builtin_amdgcn_sched_barrier(0);
    if (t + 1 < NKT) stageB();
    if (t + 2 < NKT) stageA(t & 1);
  }

  // epilogue (C^T): QKV scatter (head-major), relu, q-scale
#pragma unroll
  for (int mt = 0; mt < 4; ++mt) {
    const int mrow = (int)m0 + wm * 64 + mt * 16 + r15;
    int win = mrow / 49, nn = mrow - win * 49;
#pragma unroll
    for (int nt = 0; nt < 4; ++nt) {
      const int col0 = n0 + wn * 64 + nt * 16 + g4 * 4;
      f32x4 bv = *(const f32x4*)&bias[col0];
      f32x4 v;
#pragma unroll
      for (int j = 0; j < 4; ++j) v[j] = acc[nt][mt][j] + bv[j];
      int s = col0 >> 8, head = (col0 >> 5) & 7, d0 = col0 & 31;
      float sc = (s == 0) ? ATT_SCALE : 1.f;
#pragma unroll
      for (int j = 0; j < 4; ++j) v[j] = fmaxf(v[j], 0.f) * sc;
      u16* dst = (u16*)p0 + (size_t)s * ((size_t)NTOK * CC);
      *(uint2*)&dst[(((size_t)(win * NHEAD + head)) * NWT + nn) * HDIM + d0] =
          make_uint2(f2b2(v[0], v[1]), f2b2(v[2], v[3]));
    }
  }
}

// ---------------- PROJ (128x256, BK=64, 512 thr) + residual + FUSED LN2
__global__ __launch_bounds__(512)
void gemm_ln_k(const u16* __restrict__ A, const u16* __restrict__ BT,
               const float* __restrict__ bias, const float* __restrict__ xres,
               const float* __restrict__ g2, const float* __restrict__ be2,
               u16* __restrict__ x2, u16* __restrict__ xn2) {
  constexpr int K = 256;
  constexpr int NKT = 4;
  __shared__ u16 aL[2][128 * 64];   // 32KB
  __shared__ u16 bL[256 * 64];      // 32KB single
  __shared__ float st[4 * 128 * 2]; // 4KB stats
  const int tid = threadIdx.x;
  const int lane = tid & 63;
  const int wv = tid >> 6;
  const int wm = wv >> 2;
  const int wn = wv & 3;
  const int r15 = lane & 15;
  const int g4 = lane >> 4;

  int by = blockIdx.x;
  {
    int nwg = gridDim.x;
    int q = nwg >> 3, r = nwg & 7;
    int xcd = by & 7, idx = by >> 3;
    by = (xcd < r ? xcd * (q + 1) : r * (q + 1) + (xcd - r) * q) + idx;
  }
  const long m0 = (long)by * 128;

  f32x4 acc[4][4] = {};

  const u16* pA[2];
  int la[2];
#pragma unroll
  for (int it = 0; it < 2; ++it) {
    int slot = tid + 512 * it;
    int row = slot >> 3, c8 = slot & 7;
    int cs = c8 ^ (row & 7);
    pA[it] = &A[(m0 + row) * K + cs * 8];
    la[it] = slot * 8;
  }
  const u16* pB[4];
  int lb[4];
#pragma unroll
  for (int it = 0; it < 4; ++it) {
    int slot = tid + 512 * it;
    int row = slot >> 3, c8 = slot & 7;
    int cs = c8 ^ (row & 7);
    pB[it] = &BT[(size_t)row * K + cs * 8];
    lb[it] = slot * 8;
  }
  int aoff[2][4], boff[2][4];
#pragma unroll
  for (int kk = 0; kk < 2; ++kk)
#pragma unroll
    for (int m = 0; m < 4; ++m) {
      int rowa = wm * 64 + m * 16 + r15;
      aoff[kk][m] = rowa * 64 + (((kk * 4 + g4) ^ (rowa & 7)) << 3);
      int rowb = wn * 64 + m * 16 + r15;
      boff[kk][m] = rowb * 64 + (((kk * 4 + g4) ^ (rowb & 7)) << 3);
    }

  auto stageA = [&](int bufi) {
#pragma unroll
    for (int it = 0; it < 2; ++it) { gload_lds16(pA[it], &aL[bufi][la[it]]); pA[it] += 64; }
  };
  auto stageB = [&]() {
#pragma unroll
    for (int it = 0; it < 4; ++it) { gload_lds16(pB[it], &bL[lb[it]]); pB[it] += 64; }
  };

  stageB();
  stageA(0);
  stageA(1);

  for (int t = 0; t < NKT; ++t) {
    if (t + 1 < NKT) asm volatile("s_waitcnt vmcnt(2)" ::: "memory");
    else             asm volatile("s_waitcnt vmcnt(0)" ::: "memory");
    __builtin_amdgcn_sched_barrier(0);
    __builtin_amdgcn_s_barrier();
    __builtin_amdgcn_sched_barrier(0);
    {
      const u16* ab = aL[t & 1];
#pragma unroll
      for (int kk = 0; kk < 2; ++kk) {
        bf16x8 af[4], bfr[4];
#pragma unroll
        for (int m = 0; m < 4; ++m) af[m] = *(const bf16x8*)&ab[aoff[kk][m]];
#pragma unroll
        for (int n = 0; n < 4; ++n) bfr[n] = *(const bf16x8*)&bL[boff[kk][n]];
#pragma unroll
        for (int n = 0; n < 4; ++n)
#pragma unroll
          for (int m = 0; m < 4; ++m)
            acc[n][m] = __builtin_amdgcn_mfma_f32_16x16x32_bf16(bfr[n], af[m], acc[n][m], 0, 0, 0);
      }
    }
    __builtin_amdgcn_sched_barrier(0);
    __builtin_amdgcn_s_barrier();
    __builtin_amdgcn_sched_barrier(0);
    if (t + 1 < NKT) stageB();
    if (t + 2 < NKT) stageA(t & 1);
  }

  // ---- epilogue: v = x[pix] + proj + bias; x2(bf16, windowed); LN -> xn2
  size_t pix[4];
  float s1[4] = {}, s2[4] = {};
#pragma unroll
  for (int mt = 0; mt < 4; ++mt) {
    const int mrow = (int)m0 + wm * 64 + mt * 16 + r15;
    int win = mrow / 49, nn = mrow - win * 49;
    int b = win >> 6, wh = (win >> 3) & 7, ww = win & 7;
    int i = nn / 7, jj = nn - i * 7;
    int h = wh * 7 + i + 3; if (h >= 56) h -= 56;
    int w = ww * 7 + jj + 3; if (w >= 56) w -= 56;
    pix[mt] = (size_t)((b * 56 + h) * 56 + w);
#pragma unroll
    for (int nt = 0; nt < 4; ++nt) {
      const int col0 = wn * 64 + nt * 16 + g4 * 4;
      f32x4 bv = *(const f32x4*)&bias[col0];
      f32x4 r = *(const f32x4*)&xres[pix[mt] * CC + col0];
      f32x4 v;
#pragma unroll
      for (int j = 0; j < 4; ++j) {
        v[j] = acc[nt][mt][j] + bv[j] + r[j];
        s1[mt] += v[j];
        s2[mt] += v[j] * v[j];
      }
      *(uint2*)&x2[(size_t)mrow * CC + col0] =
          make_uint2(f2b2(v[0], v[1]), f2b2(v[2], v[3]));
      acc[nt][mt] = v;
    }
    s1[mt] += __shfl_xor(s1[mt], 16);  s1[mt] += __shfl_xor(s1[mt], 32);
    s2[mt] += __shfl_xor(s2[mt], 16);  s2[mt] += __shfl_xor(s2[mt], 32);
    if (g4 == 0) {
      int wrow = wm * 64 + mt * 16 + r15;
      st[(wn * 128 + wrow) * 2 + 0] = s1[mt];
      st[(wn * 128 + wrow) * 2 + 1] = s2[mt];
    }
  }
  __syncthreads();
#pragma unroll
  for (int mt = 0; mt < 4; ++mt) {
    const int mrow = (int)m0 + wm * 64 + mt * 16 + r15;
    int wrow = wm * 64 + mt * 16 + r15;
    float t1 = 0.f, t2 = 0.f;
#pragma unroll
    for (int w2 = 0; w2 < 4; ++w2) {
      t1 += st[(w2 * 128 + wrow) * 2 + 0];
      t2 += st[(w2 * 128 + wrow) * 2 + 1];
    }
    float mean = t1 * (1.f / 256.f);
    float var = t2 * (1.f / 256.f) - mean * mean;
    float rstd = rsqrtf(var + 1e-5f);
#pragma unroll
    for (int nt = 0; nt < 4; ++nt) {
      const int col0 = wn * 64 + nt * 16 + g4 * 4;
      f32x4 gv = *(const f32x4*)&g2[col0];
      f32x4 bv = *(const f32x4*)&be2[col0];
      float y0 = (acc[nt][mt][0] - mean) * rstd * gv[0] + bv[0];
      float y1 = (acc[nt][mt][1] - mean) * rstd * gv[1] + bv[1];
      float y2 = (acc[nt][mt][2] - mean) * rstd * gv[2] + bv[2];
      float y3 = (acc[nt][mt][3] - mean) * rstd * gv[3] + bv[3];
      *(uint2*)&xn2[(size_t)mrow * CC + col0] = make_uint2(f2b2(y0, y1), f2b2(y2, y3));
    }
  }
}

// ---------------- FUSED MLP v2: out = x2 + gelu(xn@fc1+b1)@fc2 + b2 (h in LDS only)
// r18: double-chunk (256 mlp-cols per stage-1 pass) -> 2x MFMA per barrier phase,
// -25% barriers; fast sigmoid-GELU (8 VALU ops vs ~13). LDS 80KB -> 2 blocks/CU.
__global__ __launch_bounds__(512, 4)
void mlp_fused_k(const u16* __restrict__ xn, const u16* __restrict__ fc1T,
                 const u16* __restrict__ fc2T, const float* __restrict__ b1,
                 const float* __restrict__ b2v, const u16* __restrict__ x2,
                 float* __restrict__ outp) {
  __shared__ u16 lds[40960];           // 80KB
  u16* shA0 = lds;                     // [0,4096)       8KB  A buf0 (64x64)
  u16* shA1 = lds + 4096;              // [4096,8192)    8KB  A buf1
  u16* shB1 = lds + 8192;              // [8192,24576)  32KB  B1 (256x64)
  u16* shB2 = lds;                     // [0,16384)     32KB  B2 (aliases A+B1 head)
  u16* shH  = lds + 24576;             // [24576,40960) 32KB  h chunk (64x256)

  const int tid = threadIdx.x;
  const int lane = tid & 63;
  const int wv = tid >> 6;             // 8 waves
  const int wmw = wv >> 2;             // 0..1: 32-row half
  const int wnw = wv & 3;              // 0..3: 64-col quarter
  const int r15 = lane & 15;
  const int g4 = lane >> 4;

  int by = blockIdx.x;
  {
    int nwg = gridDim.x;
    int q = nwg >> 3, r = nwg & 7;
    int xcd = by & 7, idx = by >> 3;
    by = (xcd < r ? xcd * (q + 1) : r * (q + 1) + (xcd - r) * q) + idx;
  }
  const long m0 = (long)by * 64;

  // ---- staging thread->slot maps
  // A: 64x64 (8KB): 1 gload/thread
  const int rowA = tid >> 3, csA = (tid & 7) ^ (rowA & 7);
  const u16* pAbase = &xn[(m0 + rowA) * 256 + csA * 8];
  // B1: 256x64 (32KB): 4 gloads/thread
  int lb1[4];
  const u16* pB1base[4];
#pragma unroll
  for (int it = 0; it < 4; ++it) {
    int slot = tid + 512 * it;
    int row = slot >> 3;
    int cs = (slot & 7) ^ (row & 7);
    pB1base[it] = &fc1T[(size_t)row * 256 + cs * 8];        // + hc2*256*256 + t*64
    lb1[it] = slot * 8;
  }
  // B2: 256x64 (32KB): 4 gloads/thread
  int lb2[4];
  const u16* pB2base[4];
#pragma unroll
  for (int it = 0; it < 4; ++it) {
    int slot = tid + 512 * it;
    int row = slot >> 3;
    int cs = (slot & 7) ^ (row & 7);
    pB2base[it] = &fc2T[(size_t)row * 1024 + cs * 8];       // + hc2*256 + kt*64
    lb2[it] = slot * 8;
  }

  // ---- hoisted read offsets
  // stage1: A rows wmw*32+mt*16+r15 (mt<2); B1 rows wnw*64+nt*16+r15 (nt<4)
  int a1off[2][2], b1off[2][4];
#pragma unroll
  for (int kk = 0; kk < 2; ++kk) {
#pragma unroll
    for (int m = 0; m < 2; ++m) {
      int ra = wmw * 32 + m * 16 + r15;
      a1off[kk][m] = ra * 64 + (((kk * 4 + g4) ^ (ra & 7)) << 3);
    }
#pragma unroll
    for (int n = 0; n < 4; ++n) {
      int rb = wnw * 64 + n * 16 + r15;
      b1off[kk][n] = rb * 64 + (((kk * 4 + g4) ^ (rb & 7)) << 3);
    }
  }
  // stage2: B2 rows wnw*64+nt*16+r15 (nt<4)
  int b2off[2][4];
#pragma unroll
  for (int kk = 0; kk < 2; ++kk)
#pragma unroll
    for (int n = 0; n < 4; ++n) {
      int rb = wnw * 64 + n * 16 + r15;
      b2off[kk][n] = rb * 64 + (((kk * 4 + g4) ^ (rb & 7)) << 3);
    }

  f32x4 oacc[4][2] = {};   // [nt(out col)][mt(row)]

  for (int hc2 = 0; hc2 < 4; ++hc2) {
    // ======== stage 1: acc1 = xn @ fc1T[hc2]  (M64 x N256, K=256) ========
    const size_t b1chunk = (size_t)hc2 * 256 * 256;
    // prologue: B1(t0)[4] + A(t0)[1] + A(t1)[1] = 6 outstanding
    gload_lds16(pB1base[0] + b1chunk, &shB1[lb1[0]]);
    gload_lds16(pB1base[1] + b1chunk, &shB1[lb1[1]]);
    gload_lds16(pB1base[2] + b1chunk, &shB1[lb1[2]]);
    gload_lds16(pB1base[3] + b1chunk, &shB1[lb1[3]]);
    gload_lds16(pAbase,      &shA0[tid * 8]);
    gload_lds16(pAbase + 64, &shA1[tid * 8]);

    f32x4 acc1[4][2] = {};   // [nt][mt]
    for (int t = 0; t < 4; ++t) {
      if (t + 1 < 4) asm volatile("s_waitcnt vmcnt(1)" ::: "memory");
      else           asm volatile("s_waitcnt vmcnt(0)" ::: "memory");
      __builtin_amdgcn_sched_barrier(0);
      __builtin_amdgcn_s_barrier();
      __builtin_amdgcn_sched_barrier(0);
      {
        const u16* ab = (t & 1) ? shA1 : shA0;
#pragma unroll
        for (int kk = 0; kk < 2; ++kk) {
          bf16x8 af[2], bfr[4];
#pragma unroll
          for (int m = 0; m < 2; ++m) af[m] = *(const bf16x8*)&ab[a1off[kk][m]];
#pragma unroll
          for (int n = 0; n < 4; ++n) bfr[n] = *(const bf16x8*)&shB1[b1off[kk][n]];
#pragma unroll
          for (int n = 0; n < 4; ++n)
#pragma unroll
            for (int m = 0; m < 2; ++m)
              acc1[n][m] = __builtin_amdgcn_mfma_f32_16x16x32_bf16(bfr[n], af[m], acc1[n][m], 0, 0, 0);
        }
      }
      __builtin_amdgcn_sched_barrier(0);
      __builtin_amdgcn_s_barrier();
      __builtin_amdgcn_sched_barrier(0);
      if (t + 1 < 4) {
        gload_lds16(pB1base[0] + b1chunk + (t + 1) * 64, &shB1[lb1[0]]);
        gload_lds16(pB1base[1] + b1chunk + (t + 1) * 64, &shB1[lb1[1]]);
        gload_lds16(pB1base[2] + b1chunk + (t + 1) * 64, &shB1[lb1[2]]);
        gload_lds16(pB1base[3] + b1chunk + (t + 1) * 64, &shB1[lb1[3]]);
      }
      if (t + 2 < 4) {
        u16* dst = (t & 1) ? shA1 : shA0;   // buffer (t+2)&1 == t&1
        gload_lds16(pAbase + (t + 2) * 64, &dst[tid * 8]);
      }
    }
    // A/B1 region free; shH free. Issue B2 kt0 now (L2 latency hides under GELU).
    gload_lds16(pB2base[0] + hc2 * 256, &shB2[lb2[0]]);
    gload_lds16(pB2base[1] + hc2 * 256, &shB2[lb2[1]]);
    gload_lds16(pB2base[2] + hc2 * 256, &shB2[lb2[2]]);
    gload_lds16(pB2base[3] + hc2 * 256, &shB2[lb2[3]]);

    // fast GELU -> h chunk in LDS (C^T layout; 32-chunk XOR swizzle)
#pragma unroll
    for (int mt = 0; mt < 2; ++mt) {
      const int hrow = wmw * 32 + mt * 16 + r15;
#pragma unroll
      for (int nt = 0; nt < 4; ++nt) {
        const int col0 = wnw * 64 + nt * 16 + g4 * 4;
        f32x4 bv = *(const f32x4*)&b1[hc2 * 256 + col0];
        f32x4 v;
#pragma unroll
        for (int j = 0; j < 4; ++j) {
          float u = acc1[nt][mt][j] + bv[j];
          float u2 = u * u;
          float tt = u * fmaf(0.044715f, u2, 1.f);
          float e = exp2f(tt * -2.3022029f);        // e^{-2*0.79788456*tt}
          v[j] = u * __builtin_amdgcn_rcpf(1.f + e);
        }
        int hidx = hrow * 256 + (((col0 >> 3) ^ (hrow & 31)) << 3) + (col0 & 4);
        *(uint2*)&shH[hidx] = make_uint2(f2b2(v[0], v[1]), f2b2(v[2], v[3]));
      }
    }
    asm volatile("s_waitcnt lgkmcnt(0)" ::: "memory");
    __builtin_amdgcn_sched_barrier(0);
    asm volatile("s_waitcnt vmcnt(0)" ::: "memory");   // B2 kt0 landed
    __builtin_amdgcn_sched_barrier(0);
    __builtin_amdgcn_s_barrier();                      // h + B2 kt0 visible
    __builtin_amdgcn_sched_barrier(0);

    // ======== stage 2: oacc += h @ fc2T[:, hc2*256..)  (M64 x N256, K=256) ====
#pragma unroll
    for (int kt = 0; kt < 4; ++kt) {
#pragma unroll
      for (int kk = 0; kk < 2; ++kk) {
        bf16x8 af[2], bfr[4];
#pragma unroll
        for (int m = 0; m < 2; ++m) {
          int hrow = wmw * 32 + m * 16 + r15;
          int kchunk = kt * 8 + kk * 4 + g4;
          af[m] = *(const bf16x8*)&shH[hrow * 256 + ((kchunk ^ (hrow & 31)) << 3)];
        }
#pragma unroll
        for (int n = 0; n < 4; ++n) bfr[n] = *(const bf16x8*)&shB2[b2off[kk][n]];
#pragma unroll
        for (int n = 0; n < 4; ++n)
#pragma unroll
          for (int m = 0; m < 2; ++m)
            oacc[n][m] = __builtin_amdgcn_mfma_f32_16x16x32_bf16(bfr[n], af[m], oacc[n][m], 0, 0, 0);
      }
      __builtin_amdgcn_sched_barrier(0);
      __builtin_amdgcn_s_barrier();     // all waves done with shB2 (kt)
      __builtin_amdgcn_sched_barrier(0);
      if (kt + 1 < 4) {
        gload_lds16(pB2base[0] + hc2 * 256 + (kt + 1) * 64, &shB2[lb2[0]]);
        gload_lds16(pB2base[1] + hc2 * 256 + (kt + 1) * 64, &shB2[lb2[1]]);
        gload_lds16(pB2base[2] + hc2 * 256 + (kt + 1) * 64, &shB2[lb2[2]]);
        gload_lds16(pB2base[3] + hc2 * 256 + (kt + 1) * 64, &shB2[lb2[3]]);
        asm volatile("s_waitcnt vmcnt(0)" ::: "memory");
        __builtin_amdgcn_sched_barrier(0);
        __builtin_amdgcn_s_barrier();   // B2 kt+1 visible
        __builtin_amdgcn_sched_barrier(0);
      }
    }
    // trailing barrier of kt=3 fences next chunk's A/B1 staging
  }

  // ======== epilogue: out = x2 + oacc + b2, reverse-shift scatter ========
#pragma unroll
  for (int mt = 0; mt < 2; ++mt) {
    const int mrow = (int)m0 + wmw * 32 + mt * 16 + r15;
    int win = mrow / 49, nn = mrow - win * 49;
    int b = win >> 6, wh = (win >> 3) & 7, ww = win & 7;
    int i = nn / 7, jj = nn - i * 7;
    int h = wh * 7 + i + 3; if (h >= 56) h -= 56;
    int w = ww * 7 + jj + 3; if (w >= 56) w -= 56;
    size_t pix = (size_t)((b * 56 + h) * 56 + w);
#pragma unroll
    for (int nt = 0; nt < 4; ++nt) {
      const int col0 = wnw * 64 + nt * 16 + g4 * 4;
      f32x4 bv = *(const f32x4*)&b2v[col0];
      f32x4 v;
#pragma unroll
      for (int j = 0; j < 4; ++j) v[j] = oacc[nt][mt][j] + bv[j];
      uint2 rb = *(const uint2*)&x2[(size_t)mrow * CC + col0];
      v[0] += b2f((u16)(rb.x & 0xffffu));
      v[1] += b2f((u16)(rb.x >> 16));
      v[2] += b2f((u16)(rb.y & 0xffffu));
      v[3] += b2f((u16)(rb.y >> 16));
      *(f32x4*)&outp[pix * CC + col0] = v;
    }
  }
}

// ---------------- MFMA window attention: 1 wave = 1 (window, head), 4 waves/block
__global__ __launch_bounds__(256)
void attn_mfma_k(const u16* __restrict__ q, const u16* __restrict__ k2,
                 const u16* __restrict__ v2, const float* __restrict__ lut,
                 u16* __restrict__ out) {
  __shared__ u16 P_lds[4][64 * 72];
  const int tid = threadIdx.x;
  const int wv = tid >> 6;
  const int lane = tid & 63;
  const int c = lane & 15;
  const int g = lane >> 4;
  const int blk = blockIdx.x * 4 + wv;
  const int head = blk & 7;
  const int win = blk >> 3;
  const int wimg = win & 63;
  const int wh = wimg >> 3, ww = wimg & 7;
  const size_t base = (size_t)blk * (NWT * HDIM);
  u16* Pw = P_lds[wv];

  bf16x8 kf[4], qf[4];
#pragma unroll
  for (int t = 0; t < 4; ++t) {
    kf[t] = *(const bf16x8*)&k2[base + (size_t)(t * 16 + c) * HDIM + g * 8];
    qf[t] = *(const bf16x8*)&q [base + (size_t)(t * 16 + c) * HDIM + g * 8];
  }
  bf16x8 vf[2][2];
#pragma unroll
  for (int kcc = 0; kcc < 2; ++kcc)
#pragma unroll
    for (int td = 0; td < 2; ++td)
#pragma unroll
      for (int jj = 0; jj < 8; ++jj) {
        int m = kcc * 32 + g * 8 + jj;
        m = m < 49 ? m : 48;
        vf[kcc][td][jj] = (short)v2[base + (size_t)m * HDIM + td * 16 + c];
      }

  f32x4 acc[4][4] = {};
#pragma unroll
  for (int tm = 0; tm < 4; ++tm)
#pragma unroll
    for (int tn = 0; tn < 4; ++tn)
      acc[tm][tn] = __builtin_amdgcn_mfma_f32_16x16x32_bf16(kf[tm], qf[tn], acc[tm][tn], 0, 0, 0);

  const float* lrow = &lut[(size_t)head * 64 * 64];
  int Ln[4];
#pragma unroll
  for (int tn = 0; tn < 4; ++tn) {
    int n = tn * 16 + c;
    int i1 = (n * 9363) >> 16;
    int j1 = n - i1 * 7;
    int rh = (wh < 7) ? 0 : (i1 < 4 ? 1 : 2);
    int rw = (ww < 7) ? 0 : (j1 < 4 ? 1 : 2);
    Ln[tn] = rh * 3 + rw;
  }
  float colmax[4] = {0.f, 0.f, 0.f, 0.f};
#pragma unroll
  for (int tm = 0; tm < 4; ++tm)
#pragma unroll
    for (int j = 0; j < 4; ++j) {
      int m = tm * 16 + g * 4 + j;
      int i2 = (m * 9363) >> 16;
      int j2 = m - i2 * 7;
      int rh = (wh < 7) ? 0 : (i2 < 4 ? 1 : 2);
      int rw = (ww < 7) ? 0 : (j2 < 4 ? 1 : 2);
      int Lm = rh * 3 + rw;
#pragma unroll
      for (int tn = 0; tn < 4; ++tn) {
        float s = acc[tm][tn][j] + lrow[m * 64 + tn * 16 + c];
        s = fmaxf(s, 0.f);
        if (Lm != Ln[tn]) s = 0.f;
        acc[tm][tn][j] = s;
        colmax[tn] = fmaxf(colmax[tn], s);
      }
    }
#pragma unroll
  for (int tn = 0; tn < 4; ++tn) {
    colmax[tn] = fmaxf(colmax[tn], __shfl_xor(colmax[tn], 16));
    colmax[tn] = fmaxf(colmax[tn], __shfl_xor(colmax[tn], 32));
  }
  float colsum[4] = {0.f, 0.f, 0.f, 0.f};
#pragma unroll
  for (int tm = 0; tm < 4; ++tm)
#pragma unroll
    for (int j = 0; j < 4; ++j) {
      int m = tm * 16 + g * 4 + j;
      bool mvalid = (m < NWT);
#pragma unroll
      for (int tn = 0; tn < 4; ++tn) {
        float e = mvalid ? __expf(acc[tm][tn][j] - colmax[tn]) : 0.f;
        acc[tm][tn][j] = e;
        colsum[tn] += e;
      }
    }
#pragma unroll
  for (int tn = 0; tn < 4; ++tn) {
    colsum[tn] += __shfl_xor(colsum[tn], 16);
    colsum[tn] += __shfl_xor(colsum[tn], 32);
    colsum[tn] = 1.f / colsum[tn];
  }

#pragma unroll
  for (int tn = 0; tn < 4; ++tn) {
    int n = tn * 16 + c;
#pragma unroll
    for (int tm = 0; tm < 4; ++tm) {
      float r = colsum[tn];
      *(uint2*)&Pw[n * 72 + tm * 16 + g * 4] =
          make_uint2(f2b2(acc[tm][tn][0] * r, acc[tm][tn][1] * r),
                     f2b2(acc[tm][tn][2] * r, acc[tm][tn][3] * r));
    }
  }

  f32x4 oacc[4][2] = {};
#pragma unroll
  for (int kcc = 0; kcc < 2; ++kcc) {
    bf16x8 pf[4];
#pragma unroll
    for (int tr = 0; tr < 4; ++tr)
      pf[tr] = *(const bf16x8*)&Pw[(tr * 16 + c) * 72 + kcc * 32 + g * 8];
#pragma unroll
    for (int tr = 0; tr < 4; ++tr)
#pragma unroll
      for (int td = 0; td < 2; ++td)
        oacc[tr][td] = __builtin_amdgcn_mfma_f32_16x16x32_bf16(pf[tr], vf[kcc][td], oacc[tr][td], 0, 0, 0);
  }

#pragma unroll
  for (int tr = 0; tr < 4; ++tr)
#pragma unroll
    for (int j = 0; j < 4; ++j) {
      int n = tr * 16 + g * 4 + j;
      if (n < NWT) {
#pragma unroll
        for (int td = 0; td < 2; ++td) {
          int d = td * 16 + c;
          out[((size_t)(win * NWT + n)) * CC + head * HDIM + d] =
              f2b(fmaxf(oacc[tr][td][j], 0.f));
        }
      }
    }
}

// ---------------- launch
extern "C" void kernel_launch(void* const* d_in, const int* in_sizes, int n_in,
                              void* d_out, int out_size, void* d_ws, size_t ws_size,
                              hipStream_t stream) {
  const float* x      = (const float*)d_in[0];
  const float* gamma1 = (const float*)d_in[1];
  const float* beta1  = (const float*)d_in[2];
  const float* w_qkv  = (const float*)d_in[3];
  const float* b_qkv  = (const float*)d_in[4];
  const float* rpb    = (const float*)d_in[5];
  const float* w_proj = (const float*)d_in[6];
  const float* b_proj = (const float*)d_in[7];
  const float* gamma2 = (const float*)d_in[8];
  const float* beta2  = (const float*)d_in[9];
  const float* w_fc1  = (const float*)d_in[10];
  const float* b_fc1  = (const float*)d_in[11];
  const float* w_fc2  = (const float*)d_in[12];
  const float* b_fc2  = (const float*)d_in[13];
  float* out = (float*)d_out;

  char* ws = (char*)d_ws;
  size_t off = 0;
  auto alloc = [&](size_t bytes) { void* p = ws + off; off = (off + bytes + 255) & ~(size_t)255; return p; };

  u16* wqkvT = (u16*)alloc(768 * 256 * 2);
  u16* wprojT = (u16*)alloc(256 * 256 * 2);
  u16* wfc1T = (u16*)alloc(1024 * 256 * 2);
  u16* wfc2T = (u16*)alloc(256 * 1024 * 2);
  float* lut = (float*)alloc(8 * 64 * 64 * 4);
  // region2 (51.4MB): xw -> attn_out   (strictly sequential lifetimes)
  u16* region2 = (u16*)alloc((size_t)NTOK * CC * 2);
  // region1 (154.2MB): q|k|v  ->  x2 (bf16 51.4MB, windowed) + xn2 (bf16 51.4MB)
  char* region1 = (char*)alloc((size_t)3 * NTOK * CC * 2);

  u16* xw = region2;
  u16* qb = (u16*)region1;
  u16* kb = qb + (size_t)NTOK * CC;
  u16* vb = kb + (size_t)NTOK * CC;
  u16* attn_out = region2;
  u16* x2 = (u16*)region1;
  u16* xn2 = x2 + (size_t)NTOK * CC;

  if (ws_size < off) return;

  prep_k<<<3200, 256, 0, stream>>>(w_qkv, w_proj, w_fc1, w_fc2, rpb,
                                   wqkvT, wprojT, wfc1T, wfc2T, lut);

  // LN1 + shift + partition
  ln_k<<<NTOK / 4, 256, 0, stream>>>(x, gamma1, beta1, xw);

  // QKV GEMM: M=100352, N=768, K=256
  gemm_k<EPI_QKV, 4><<<dim3(768 / BN, NTOK / BM), 256, 0, stream>>>(
      xw, wqkvT, b_qkv, (void*)qb, nullptr);

  // fused MFMA window attention
  attn_mfma_k<<<NWIN * NHEAD / 4, 256, 0, stream>>>(qb, kb, vb, lut, attn_out);

  // PROJ (128x256 tile) + reverse-shift residual + fused LN2 (windowed bf16 out)
  gemm_ln_k<<<NTOK / 128, 512, 0, stream>>>(
      attn_out, wprojT, b_proj, x, gamma2, beta2, x2, xn2);

  // fused MLP v2: single dispatch, h lives in LDS only
  mlp_fused_k<<<NTOK / 64, 512, 0, stream>>>(
      xn2, wfc1T, wfc2T, b_fc1, b_fc2, x2, out);
}

// Round 19
// 459.321 us; speedup vs baseline: 1.0701x; 1.0701x over previous
//
#include <hip/hip_runtime.h>
#include <stdint.h>

typedef unsigned short u16;
typedef short bf16x8 __attribute__((ext_vector_type(8)));
typedef float f32x4 __attribute__((ext_vector_type(4)));

#define NTOK 100352      // B*H*W tokens
#define NWIN 2048        // B * 64 windows
#define CC 256
#define NHEAD 8
#define HDIM 32
#define NWT 49           // tokens per window
#define MLPD 1024
#define ATT_SCALE 0.17677669529663687f  // 32^-0.5

__device__ __forceinline__ u16 f2b(float f) {
  union { float f; uint32_t u; } c; c.f = f;
  return (u16)((c.u + 0x7fffu + ((c.u >> 16) & 1u)) >> 16);
}
__device__ __forceinline__ float b2f(u16 h) {
  union { uint32_t u; float f; } c; c.u = ((uint32_t)h) << 16;
  return c.f;
}
// packed f32x2 -> bf16x2 (RNE), 1 VALU op
__device__ __forceinline__ uint32_t f2b2(float lo, float hi) {
  uint32_t r;
  asm("v_cvt_pk_bf16_f32 %0, %1, %2" : "=v"(r) : "v"(lo), "v"(hi));
  return r;
}

__device__ __forceinline__ void gload_lds16(const void* g, void* l) {
  __builtin_amdgcn_global_load_lds((const __attribute__((address_space(1))) void*)g,
                                   (__attribute__((address_space(3))) void*)l, 16, 0, 0);
}

// ---------------- prep: all weight transposes + bias LUT in ONE dispatch
__global__ __launch_bounds__(256)
void prep_k(const float* __restrict__ wqkv, const float* __restrict__ wproj,
            const float* __restrict__ wfc1, const float* __restrict__ wfc2,
            const float* __restrict__ rpb,
            u16* __restrict__ qkvT, u16* __restrict__ projT,
            u16* __restrict__ fc1T, u16* __restrict__ fc2T, float* __restrict__ lut) {
  int i = blockIdx.x * 256 + threadIdx.x;
  if (i < 196608) {                     // wqkv: K=256, N=768
    int k = i / 768, n = i % 768;
    qkvT[(size_t)n * 256 + k] = f2b(wqkv[i]);
  } else if (i < 262144) {              // wproj: 256x256
    int j = i - 196608, k = j / 256, n = j % 256;
    projT[(size_t)n * 256 + k] = f2b(wproj[j]);
  } else if (i < 524288) {              // wfc1: K=256, N=1024
    int j = i - 262144, k = j / 1024, n = j % 1024;
    fc1T[(size_t)n * 256 + k] = f2b(wfc1[j]);
  } else if (i < 786432) {              // wfc2: K=1024, N=256
    int j = i - 524288, k = j / 256, n = j % 256;
    fc2T[(size_t)n * 1024 + k] = f2b(wfc2[j]);
  } else if (i < 819200) {              // bias LUT lut[h][m][n], 64x64 padded
    int j = i - 786432;
    int h = j >> 12, m = (j >> 6) & 63, n = j & 63;
    float v = 0.f;
    if (m < 49 && n < 49) {
      int i1 = n / 7, j1 = n % 7, i2 = m / 7, j2 = m % 7;
      v = rpb[((i1 - i2 + 6) * 13 + (j1 - j2 + 6)) * 8 + h];
    }
    lut[j] = v;
  }
}

// ---------------- LN1 + cyclic-shift + window-partition -> bf16 tokens
__global__ __launch_bounds__(256)
void ln_k(const float* __restrict__ x, const float* __restrict__ g,
          const float* __restrict__ be, u16* __restrict__ out) {
  int token = blockIdx.x * 4 + (threadIdx.x >> 6);
  int lane = threadIdx.x & 63;
  int win = token / 49, nn = token % 49;
  int b = win >> 6, wh = (win >> 3) & 7, ww = win & 7;
  int i = nn / 7, j = nn % 7;
  int h = wh * 7 + i + 3; if (h >= 56) h -= 56;
  int w = ww * 7 + j + 3; if (w >= 56) w -= 56;
  size_t src = ((size_t)((b * 56 + h) * 56 + w)) * CC;
  f32x4 v = *(const f32x4*)&x[src + lane * 4];
  float s1 = v[0] + v[1] + v[2] + v[3];
  float s2 = v[0]*v[0] + v[1]*v[1] + v[2]*v[2] + v[3]*v[3];
#pragma unroll
  for (int o = 32; o; o >>= 1) { s1 += __shfl_xor(s1, o); s2 += __shfl_xor(s2, o); }
  float mean = s1 * (1.f / 256.f);
  float var = s2 * (1.f / 256.f) - mean * mean;
  float rstd = rsqrtf(var + 1e-5f);
  f32x4 gv = *(const f32x4*)&g[lane * 4];
  f32x4 bv = *(const f32x4*)&be[lane * 4];
  float y0 = (v[0]-mean)*rstd*gv[0] + bv[0];
  float y1 = (v[1]-mean)*rstd*gv[1] + bv[1];
  float y2 = (v[2]-mean)*rstd*gv[2] + bv[2];
  float y3 = (v[3]-mean)*rstd*gv[3] + bv[3];
  *(uint2*)&out[(size_t)token * CC + lane * 4] = make_uint2(f2b2(y0, y1), f2b2(y2, y3));
}

// ---------------- GEMM (128x128, BK=64): A dbuf (32KB) + B single-buffer (16KB)
#define BM 128
#define BN 128
enum { EPI_QKV = 0 };

template<int EPI, int NKT>
__global__ __launch_bounds__(256)
void gemm_k(const u16* __restrict__ A, const u16* __restrict__ BT,
            const float* __restrict__ bias,
            void* __restrict__ p0, const void* __restrict__ p1) {
  constexpr int K = NKT * 64;
  __shared__ u16 aL[2][BM * 64];   // 32KB double-buffered
  __shared__ u16 bL[BN * 64];      // 16KB single (staged 1 tile ahead)
  const int tid = threadIdx.x;
  const int lane = tid & 63;
  const int wv = tid >> 6;
  const int wm = wv >> 1, wn = wv & 1;

  int bx = blockIdx.x, by = blockIdx.y;
  {
    int nwg = gridDim.x * gridDim.y;
    int lin = by * gridDim.x + bx;
    int q = nwg >> 3, r = nwg & 7;
    int xcd = lin & 7, idx = lin >> 3;
    int wg = (xcd < r ? xcd * (q + 1) : r * (q + 1) + (xcd - r) * q) + idx;
    bx = wg % gridDim.x;
    by = wg / gridDim.x;
  }
  const long m0 = (long)by * BM;
  const int n0 = bx * BN;

  f32x4 acc[4][4] = {};   // [n-tile][m-tile]
  const int r15 = lane & 15;
  const int g4 = lane >> 4;

  const u16* pA[4];
  const u16* pB[4];
  int lslot[4];
#pragma unroll
  for (int it = 0; it < 4; ++it) {
    int slot = tid + 256 * it;
    int row = slot >> 3, c8 = slot & 7;
    int cs = c8 ^ (row & 7);
    pA[it] = &A[(m0 + row) * K + cs * 8];
    pB[it] = &BT[(size_t)(n0 + row) * K + cs * 8];
    lslot[it] = slot * 8;
  }
  int aoff[2][4], boff[2][4];
#pragma unroll
  for (int kk = 0; kk < 2; ++kk)
#pragma unroll
    for (int m = 0; m < 4; ++m) {
      int rowa = wm * 64 + m * 16 + r15;
      aoff[kk][m] = rowa * 64 + (((kk * 4 + g4) ^ (rowa & 7)) << 3);
      int rowb = wn * 64 + m * 16 + r15;
      boff[kk][m] = rowb * 64 + (((kk * 4 + g4) ^ (rowb & 7)) << 3);
    }

  auto stageA = [&](int bufi) {
#pragma unroll
    for (int it = 0; it < 4; ++it) { gload_lds16(pA[it], &aL[bufi][lslot[it]]); pA[it] += 64; }
  };
  auto stageB = [&]() {
#pragma unroll
    for (int it = 0; it < 4; ++it) { gload_lds16(pB[it], &bL[lslot[it]]); pB[it] += 64; }
  };

  stageB();
  stageA(0);
  stageA(1);

  for (int t = 0; t < NKT; ++t) {
    if (t + 1 < NKT) asm volatile("s_waitcnt vmcnt(4)" ::: "memory");
    else             asm volatile("s_waitcnt vmcnt(0)" ::: "memory");
    __builtin_amdgcn_sched_barrier(0);
    __builtin_amdgcn_s_barrier();
    __builtin_amdgcn_sched_barrier(0);
    {
      const u16* ab = aL[t & 1];
#pragma unroll
      for (int kk = 0; kk < 2; ++kk) {
        bf16x8 af[4], bfr[4];
#pragma unroll
        for (int m = 0; m < 4; ++m) af[m] = *(const bf16x8*)&ab[aoff[kk][m]];
#pragma unroll
        for (int n = 0; n < 4; ++n) bfr[n] = *(const bf16x8*)&bL[boff[kk][n]];
#pragma unroll
        for (int n = 0; n < 4; ++n)
#pragma unroll
          for (int m = 0; m < 4; ++m)
            acc[n][m] = __builtin_amdgcn_mfma_f32_16x16x32_bf16(bfr[n], af[m], acc[n][m], 0, 0, 0);
      }
    }
    __builtin_amdgcn_sched_barrier(0);
    __builtin_amdgcn_s_barrier();
    __builtin_amdgcn_sched_barrier(0);
    if (t + 1 < NKT) stageB();
    if (t + 2 < NKT) stageA(t & 1);
  }

  // epilogue (C^T): QKV scatter (head-major), relu, q-scale
#pragma unroll
  for (int mt = 0; mt < 4; ++mt) {
    const int mrow = (int)m0 + wm * 64 + mt * 16 + r15;
    int win = mrow / 49, nn = mrow - win * 49;
#pragma unroll
    for (int nt = 0; nt < 4; ++nt) {
      const int col0 = n0 + wn * 64 + nt * 16 + g4 * 4;
      f32x4 bv = *(const f32x4*)&bias[col0];
      f32x4 v;
#pragma unroll
      for (int j = 0; j < 4; ++j) v[j] = acc[nt][mt][j] + bv[j];
      int s = col0 >> 8, head = (col0 >> 5) & 7, d0 = col0 & 31;
      float sc = (s == 0) ? ATT_SCALE : 1.f;
#pragma unroll
      for (int j = 0; j < 4; ++j) v[j] = fmaxf(v[j], 0.f) * sc;
      u16* dst = (u16*)p0 + (size_t)s * ((size_t)NTOK * CC);
      *(uint2*)&dst[(((size_t)(win * NHEAD + head)) * NWT + nn) * HDIM + d0] =
          make_uint2(f2b2(v[0], v[1]), f2b2(v[2], v[3]));
    }
  }
}

// ---------------- PROJ (128x256, BK=64, 512 thr) + residual + FUSED LN2
__global__ __launch_bounds__(512)
void gemm_ln_k(const u16* __restrict__ A, const u16* __restrict__ BT,
               const float* __restrict__ bias, const float* __restrict__ xres,
               const float* __restrict__ g2, const float* __restrict__ be2,
               u16* __restrict__ x2, u16* __restrict__ xn2) {
  constexpr int K = 256;
  constexpr int NKT = 4;
  __shared__ u16 aL[2][128 * 64];   // 32KB
  __shared__ u16 bL[256 * 64];      // 32KB single
  __shared__ float st[4 * 128 * 2]; // 4KB stats
  const int tid = threadIdx.x;
  const int lane = tid & 63;
  const int wv = tid >> 6;
  const int wm = wv >> 2;
  const int wn = wv & 3;
  const int r15 = lane & 15;
  const int g4 = lane >> 4;

  int by = blockIdx.x;
  {
    int nwg = gridDim.x;
    int q = nwg >> 3, r = nwg & 7;
    int xcd = by & 7, idx = by >> 3;
    by = (xcd < r ? xcd * (q + 1) : r * (q + 1) + (xcd - r) * q) + idx;
  }
  const long m0 = (long)by * 128;

  f32x4 acc[4][4] = {};

  const u16* pA[2];
  int la[2];
#pragma unroll
  for (int it = 0; it < 2; ++it) {
    int slot = tid + 512 * it;
    int row = slot >> 3, c8 = slot & 7;
    int cs = c8 ^ (row & 7);
    pA[it] = &A[(m0 + row) * K + cs * 8];
    la[it] = slot * 8;
  }
  const u16* pB[4];
  int lb[4];
#pragma unroll
  for (int it = 0; it < 4; ++it) {
    int slot = tid + 512 * it;
    int row = slot >> 3, c8 = slot & 7;
    int cs = c8 ^ (row & 7);
    pB[it] = &BT[(size_t)row * K + cs * 8];
    lb[it] = slot * 8;
  }
  int aoff[2][4], boff[2][4];
#pragma unroll
  for (int kk = 0; kk < 2; ++kk)
#pragma unroll
    for (int m = 0; m < 4; ++m) {
      int rowa = wm * 64 + m * 16 + r15;
      aoff[kk][m] = rowa * 64 + (((kk * 4 + g4) ^ (rowa & 7)) << 3);
      int rowb = wn * 64 + m * 16 + r15;
      boff[kk][m] = rowb * 64 + (((kk * 4 + g4) ^ (rowb & 7)) << 3);
    }

  auto stageA = [&](int bufi) {
#pragma unroll
    for (int it = 0; it < 2; ++it) { gload_lds16(pA[it], &aL[bufi][la[it]]); pA[it] += 64; }
  };
  auto stageB = [&]() {
#pragma unroll
    for (int it = 0; it < 4; ++it) { gload_lds16(pB[it], &bL[lb[it]]); pB[it] += 64; }
  };

  stageB();
  stageA(0);
  stageA(1);

  for (int t = 0; t < NKT; ++t) {
    if (t + 1 < NKT) asm volatile("s_waitcnt vmcnt(2)" ::: "memory");
    else             asm volatile("s_waitcnt vmcnt(0)" ::: "memory");
    __builtin_amdgcn_sched_barrier(0);
    __builtin_amdgcn_s_barrier();
    __builtin_amdgcn_sched_barrier(0);
    {
      const u16* ab = aL[t & 1];
#pragma unroll
      for (int kk = 0; kk < 2; ++kk) {
        bf16x8 af[4], bfr[4];
#pragma unroll
        for (int m = 0; m < 4; ++m) af[m] = *(const bf16x8*)&ab[aoff[kk][m]];
#pragma unroll
        for (int n = 0; n < 4; ++n) bfr[n] = *(const bf16x8*)&bL[boff[kk][n]];
#pragma unroll
        for (int n = 0; n < 4; ++n)
#pragma unroll
          for (int m = 0; m < 4; ++m)
            acc[n][m] = __builtin_amdgcn_mfma_f32_16x16x32_bf16(bfr[n], af[m], acc[n][m], 0, 0, 0);
      }
    }
    __builtin_amdgcn_sched_barrier(0);
    __builtin_amdgcn_s_barrier();
    __builtin_amdgcn_sched_barrier(0);
    if (t + 1 < NKT) stageB();
    if (t + 2 < NKT) stageA(t & 1);
  }

  // ---- epilogue: v = x[pix] + proj + bias; x2(bf16, windowed); LN -> xn2
  size_t pix[4];
  float s1[4] = {}, s2[4] = {};
#pragma unroll
  for (int mt = 0; mt < 4; ++mt) {
    const int mrow = (int)m0 + wm * 64 + mt * 16 + r15;
    int win = mrow / 49, nn = mrow - win * 49;
    int b = win >> 6, wh = (win >> 3) & 7, ww = win & 7;
    int i = nn / 7, jj = nn - i * 7;
    int h = wh * 7 + i + 3; if (h >= 56) h -= 56;
    int w = ww * 7 + jj + 3; if (w >= 56) w -= 56;
    pix[mt] = (size_t)((b * 56 + h) * 56 + w);
#pragma unroll
    for (int nt = 0; nt < 4; ++nt) {
      const int col0 = wn * 64 + nt * 16 + g4 * 4;
      f32x4 bv = *(const f32x4*)&bias[col0];
      f32x4 r = *(const f32x4*)&xres[pix[mt] * CC + col0];
      f32x4 v;
#pragma unroll
      for (int j = 0; j < 4; ++j) {
        v[j] = acc[nt][mt][j] + bv[j] + r[j];
        s1[mt] += v[j];
        s2[mt] += v[j] * v[j];
      }
      *(uint2*)&x2[(size_t)mrow * CC + col0] =
          make_uint2(f2b2(v[0], v[1]), f2b2(v[2], v[3]));
      acc[nt][mt] = v;
    }
    s1[mt] += __shfl_xor(s1[mt], 16);  s1[mt] += __shfl_xor(s1[mt], 32);
    s2[mt] += __shfl_xor(s2[mt], 16);  s2[mt] += __shfl_xor(s2[mt], 32);
    if (g4 == 0) {
      int wrow = wm * 64 + mt * 16 + r15;
      st[(wn * 128 + wrow) * 2 + 0] = s1[mt];
      st[(wn * 128 + wrow) * 2 + 1] = s2[mt];
    }
  }
  __syncthreads();
#pragma unroll
  for (int mt = 0; mt < 4; ++mt) {
    const int mrow = (int)m0 + wm * 64 + mt * 16 + r15;
    int wrow = wm * 64 + mt * 16 + r15;
    float t1 = 0.f, t2 = 0.f;
#pragma unroll
    for (int w2 = 0; w2 < 4; ++w2) {
      t1 += st[(w2 * 128 + wrow) * 2 + 0];
      t2 += st[(w2 * 128 + wrow) * 2 + 1];
    }
    float mean = t1 * (1.f / 256.f);
    float var = t2 * (1.f / 256.f) - mean * mean;
    float rstd = rsqrtf(var + 1e-5f);
#pragma unroll
    for (int nt = 0; nt < 4; ++nt) {
      const int col0 = wn * 64 + nt * 16 + g4 * 4;
      f32x4 gv = *(const f32x4*)&g2[col0];
      f32x4 bv = *(const f32x4*)&be2[col0];
      float y0 = (acc[nt][mt][0] - mean) * rstd * gv[0] + bv[0];
      float y1 = (acc[nt][mt][1] - mean) * rstd * gv[1] + bv[1];
      float y2 = (acc[nt][mt][2] - mean) * rstd * gv[2] + bv[2];
      float y3 = (acc[nt][mt][3] - mean) * rstd * gv[3] + bv[3];
      *(uint2*)&xn2[(size_t)mrow * CC + col0] = make_uint2(f2b2(y0, y1), f2b2(y2, y3));
    }
  }
}

// ---------------- FUSED MLP (r17 structure + fast GELU): h lives in LDS only.
// r17 measured clean: no spills (FETCH 77MB / WRITE 100MB), 250us. r18's
// double-chunk spilled (acc1 growth past 128-VGPR cap) -> reverted; fast
// sigmoid-GELU kept (VALUBusy 37.5 -> 26.4 measured in r18).
__global__ __launch_bounds__(512, 4)
void mlp_fused_k(const u16* __restrict__ xn, const u16* __restrict__ fc1T,
                 const u16* __restrict__ fc2T, const float* __restrict__ b1,
                 const float* __restrict__ b2v, const u16* __restrict__ x2,
                 float* __restrict__ outp) {
  __shared__ u16 lds[24576];           // 48KB
  u16* shA0 = lds;                     // [0,4096)      8KB  A buf0
  u16* shA1 = lds + 4096;              // [4096,8192)   8KB  A buf1
  u16* shB1 = lds + 8192;              // [8192,16384) 16KB  B1
  u16* shB2 = lds;                     // [0,16384)    32KB  B2 (aliases A+B1)
  u16* shH  = lds + 16384;             // [16384,24576)16KB  h chunk (64x128)

  const int tid = threadIdx.x;
  const int lane = tid & 63;
  const int wv = tid >> 6;             // 8 waves
  const int wmw = wv >> 2;             // 0..1: 32-row half
  const int wnw = wv & 3;              // 0..3: col quarter
  const int r15 = lane & 15;
  const int g4 = lane >> 4;

  int by = blockIdx.x;
  {
    int nwg = gridDim.x;
    int q = nwg >> 3, r = nwg & 7;
    int xcd = by & 7, idx = by >> 3;
    by = (xcd < r ? xcd * (q + 1) : r * (q + 1) + (xcd - r) * q) + idx;
  }
  const long m0 = (long)by * 64;

  // ---- staging thread->slot maps
  const int rowA = tid >> 3, csA = (tid & 7) ^ (rowA & 7);
  const u16* pAbase = &xn[(m0 + rowA) * 256 + csA * 8];
  int rowB1[2], lb1[2];
  const u16* pB1base[2];
#pragma unroll
  for (int it = 0; it < 2; ++it) {
    int slot = tid + 512 * it;
    rowB1[it] = slot >> 3;
    int cs = (slot & 7) ^ (rowB1[it] & 7);
    pB1base[it] = &fc1T[(size_t)rowB1[it] * 256 + cs * 8];  // + hc*128*256 + t*64
    lb1[it] = slot * 8;
  }
  int lb2[4];
  const u16* pB2base[4];
#pragma unroll
  for (int it = 0; it < 4; ++it) {
    int slot = tid + 512 * it;
    int row = slot >> 3;
    int cs = (slot & 7) ^ (row & 7);
    pB2base[it] = &fc2T[(size_t)row * 1024 + cs * 8];       // + hc*128 + kt*64
    lb2[it] = slot * 8;
  }

  // ---- hoisted read offsets
  int a1off[2][2], b1off[2][2];
#pragma unroll
  for (int kk = 0; kk < 2; ++kk)
#pragma unroll
    for (int m = 0; m < 2; ++m) {
      int ra = wmw * 32 + m * 16 + r15;
      a1off[kk][m] = ra * 64 + (((kk * 4 + g4) ^ (ra & 7)) << 3);
      int rb = wnw * 32 + m * 16 + r15;
      b1off[kk][m] = rb * 64 + (((kk * 4 + g4) ^ (rb & 7)) << 3);
    }
  int b2off[2][4];
#pragma unroll
  for (int kk = 0; kk < 2; ++kk)
#pragma unroll
    for (int n = 0; n < 4; ++n) {
      int rb = wnw * 64 + n * 16 + r15;
      b2off[kk][n] = rb * 64 + (((kk * 4 + g4) ^ (rb & 7)) << 3);
    }

  f32x4 oacc[4][2] = {};   // [nt(out col)][mt(row)]

  for (int hc = 0; hc < 8; ++hc) {
    // ======== stage 1: acc1 = xn @ fc1T[hc]  (M64 x N128, K=256) ========
    const size_t b1chunk = (size_t)hc * 128 * 256;
    gload_lds16(pB1base[0] + b1chunk, &shB1[lb1[0]]);
    gload_lds16(pB1base[1] + b1chunk, &shB1[lb1[1]]);
    gload_lds16(pAbase,      &shA0[tid * 8]);
    gload_lds16(pAbase + 64, &shA1[tid * 8]);

    f32x4 acc1[2][2] = {};   // [nt][mt]
    for (int t = 0; t < 4; ++t) {
      if (t + 1 < 4) asm volatile("s_waitcnt vmcnt(1)" ::: "memory");
      else           asm volatile("s_waitcnt vmcnt(0)" ::: "memory");
      __builtin_amdgcn_sched_barrier(0);
      __builtin_amdgcn_s_barrier();
      __builtin_amdgcn_sched_barrier(0);
      {
        const u16* ab = (t & 1) ? shA1 : shA0;
#pragma unroll
        for (int kk = 0; kk < 2; ++kk) {
          bf16x8 af[2], bfr[2];
#pragma unroll
          for (int m = 0; m < 2; ++m) af[m] = *(const bf16x8*)&ab[a1off[kk][m]];
#pragma unroll
          for (int n = 0; n < 2; ++n) bfr[n] = *(const bf16x8*)&shB1[b1off[kk][n]];
#pragma unroll
          for (int n = 0; n < 2; ++n)
#pragma unroll
            for (int m = 0; m < 2; ++m)
              acc1[n][m] = __builtin_amdgcn_mfma_f32_16x16x32_bf16(bfr[n], af[m], acc1[n][m], 0, 0, 0);
        }
      }
      __builtin_amdgcn_sched_barrier(0);
      __builtin_amdgcn_s_barrier();
      __builtin_amdgcn_sched_barrier(0);
      if (t + 1 < 4) {
        gload_lds16(pB1base[0] + b1chunk + (t + 1) * 64, &shB1[lb1[0]]);
        gload_lds16(pB1base[1] + b1chunk + (t + 1) * 64, &shB1[lb1[1]]);
      }
      if (t + 2 < 4) {
        u16* dst = (t & 1) ? shA1 : shA0;   // buffer (t+2)&1 == t&1
        gload_lds16(pAbase + (t + 2) * 64, &dst[tid * 8]);
      }
    }
    // A/B1 region free; shH free. Issue B2 kt0 now (L2 latency hides under GELU).
    gload_lds16(pB2base[0] + hc * 128, &shB2[lb2[0]]);
    gload_lds16(pB2base[1] + hc * 128, &shB2[lb2[1]]);
    gload_lds16(pB2base[2] + hc * 128, &shB2[lb2[2]]);
    gload_lds16(pB2base[3] + hc * 128, &shB2[lb2[3]]);

    // fast sigmoid-GELU -> h chunk in LDS (C^T layout; XOR-swizzled chunks)
#pragma unroll
    for (int mt = 0; mt < 2; ++mt) {
      const int hrow = wmw * 32 + mt * 16 + r15;
#pragma unroll
      for (int nt = 0; nt < 2; ++nt) {
        const int col0 = wnw * 32 + nt * 16 + g4 * 4;
        f32x4 bv = *(const f32x4*)&b1[hc * 128 + col0];
        f32x4 v;
#pragma unroll
        for (int j = 0; j < 4; ++j) {
          float u = acc1[nt][mt][j] + bv[j];
          float u2 = u * u;
          float tt = u * fmaf(0.044715f, u2, 1.f);
          float e = exp2f(tt * -2.3022029f);        // e^{-2*0.79788456*tt}
          v[j] = u * __builtin_amdgcn_rcpf(1.f + e);
        }
        int hidx = hrow * 128 + (((col0 >> 3) ^ (hrow & 15)) << 3) + (col0 & 4);
        *(uint2*)&shH[hidx] = make_uint2(f2b2(v[0], v[1]), f2b2(v[2], v[3]));
      }
    }
    asm volatile("s_waitcnt lgkmcnt(0)" ::: "memory");
    __builtin_amdgcn_sched_barrier(0);
    asm volatile("s_waitcnt vmcnt(0)" ::: "memory");   // B2 kt0 landed
    __builtin_amdgcn_sched_barrier(0);
    __builtin_amdgcn_s_barrier();                      // h + B2 kt0 visible
    __builtin_amdgcn_sched_barrier(0);

    // ======== stage 2: oacc += h @ fc2T[:, hc*128..)  (M64 x N256, K=128) ====
#pragma unroll
    for (int kt = 0; kt < 2; ++kt) {
#pragma unroll
      for (int kk = 0; kk < 2; ++kk) {
        bf16x8 af[2], bfr[4];
#pragma unroll
        for (int m = 0; m < 2; ++m) {
          int hrow = wmw * 32 + m * 16 + r15;
          int kchunk = kt * 8 + kk * 4 + g4;
          af[m] = *(const bf16x8*)&shH[hrow * 128 + ((kchunk ^ (hrow & 15)) << 3)];
        }
#pragma unroll
        for (int n = 0; n < 4; ++n) bfr[n] = *(const bf16x8*)&shB2[b2off[kk][n]];
#pragma unroll
        for (int n = 0; n < 4; ++n)
#pragma unroll
          for (int m = 0; m < 2; ++m)
            oacc[n][m] = __builtin_amdgcn_mfma_f32_16x16x32_bf16(bfr[n], af[m], oacc[n][m], 0, 0, 0);
      }
      __builtin_amdgcn_sched_barrier(0);
      __builtin_amdgcn_s_barrier();     // all waves done with shB2 (kt)
      __builtin_amdgcn_sched_barrier(0);
      if (kt == 0) {
        gload_lds16(pB2base[0] + hc * 128 + 64, &shB2[lb2[0]]);
        gload_lds16(pB2base[1] + hc * 128 + 64, &shB2[lb2[1]]);
        gload_lds16(pB2base[2] + hc * 128 + 64, &shB2[lb2[2]]);
        gload_lds16(pB2base[3] + hc * 128 + 64, &shB2[lb2[3]]);
        asm volatile("s_waitcnt vmcnt(0)" ::: "memory");
        __builtin_amdgcn_sched_barrier(0);
        __builtin_amdgcn_s_barrier();   // B2 kt1 visible
        __builtin_amdgcn_sched_barrier(0);
      }
    }
  }

  // ======== epilogue: out = x2 + oacc + b2, reverse-shift scatter ========
#pragma unroll
  for (int mt = 0; mt < 2; ++mt) {
    const int mrow = (int)m0 + wmw * 32 + mt * 16 + r15;
    int win = mrow / 49, nn = mrow - win * 49;
    int b = win >> 6, wh = (win >> 3) & 7, ww = win & 7;
    int i = nn / 7, jj = nn - i * 7;
    int h = wh * 7 + i + 3; if (h >= 56) h -= 56;
    int w = ww * 7 + jj + 3; if (w >= 56) w -= 56;
    size_t pix = (size_t)((b * 56 + h) * 56 + w);
#pragma unroll
    for (int nt = 0; nt < 4; ++nt) {
      const int col0 = wnw * 64 + nt * 16 + g4 * 4;
      f32x4 bv = *(const f32x4*)&b2v[col0];
      f32x4 v;
#pragma unroll
      for (int j = 0; j < 4; ++j) v[j] = oacc[nt][mt][j] + bv[j];
      uint2 rb = *(const uint2*)&x2[(size_t)mrow * CC + col0];
      v[0] += b2f((u16)(rb.x & 0xffffu));
      v[1] += b2f((u16)(rb.x >> 16));
      v[2] += b2f((u16)(rb.y & 0xffffu));
      v[3] += b2f((u16)(rb.y >> 16));
      *(f32x4*)&outp[pix * CC + col0] = v;
    }
  }
}

// ---------------- MFMA window attention: 1 wave = 1 (window, head), 4 waves/block
__global__ __launch_bounds__(256)
void attn_mfma_k(const u16* __restrict__ q, const u16* __restrict__ k2,
                 const u16* __restrict__ v2, const float* __restrict__ lut,
                 u16* __restrict__ out) {
  __shared__ u16 P_lds[4][64 * 72];
  const int tid = threadIdx.x;
  const int wv = tid >> 6;
  const int lane = tid & 63;
  const int c = lane & 15;
  const int g = lane >> 4;
  const int blk = blockIdx.x * 4 + wv;
  const int head = blk & 7;
  const int win = blk >> 3;
  const int wimg = win & 63;
  const int wh = wimg >> 3, ww = wimg & 7;
  const size_t base = (size_t)blk * (NWT * HDIM);
  u16* Pw = P_lds[wv];

  bf16x8 kf[4], qf[4];
#pragma unroll
  for (int t = 0; t < 4; ++t) {
    kf[t] = *(const bf16x8*)&k2[base + (size_t)(t * 16 + c) * HDIM + g * 8];
    qf[t] = *(const bf16x8*)&q [base + (size_t)(t * 16 + c) * HDIM + g * 8];
  }
  bf16x8 vf[2][2];
#pragma unroll
  for (int kcc = 0; kcc < 2; ++kcc)
#pragma unroll
    for (int td = 0; td < 2; ++td)
#pragma unroll
      for (int jj = 0; jj < 8; ++jj) {
        int m = kcc * 32 + g * 8 + jj;
        m = m < 49 ? m : 48;
        vf[kcc][td][jj] = (short)v2[base + (size_t)m * HDIM + td * 16 + c];
      }

  f32x4 acc[4][4] = {};
#pragma unroll
  for (int tm = 0; tm < 4; ++tm)
#pragma unroll
    for (int tn = 0; tn < 4; ++tn)
      acc[tm][tn] = __builtin_amdgcn_mfma_f32_16x16x32_bf16(kf[tm], qf[tn], acc[tm][tn], 0, 0, 0);

  const float* lrow = &lut[(size_t)head * 64 * 64];
  int Ln[4];
#pragma unroll
  for (int tn = 0; tn < 4; ++tn) {
    int n = tn * 16 + c;
    int i1 = (n * 9363) >> 16;
    int j1 = n - i1 * 7;
    int rh = (wh < 7) ? 0 : (i1 < 4 ? 1 : 2);
    int rw = (ww < 7) ? 0 : (j1 < 4 ? 1 : 2);
    Ln[tn] = rh * 3 + rw;
  }
  float colmax[4] = {0.f, 0.f, 0.f, 0.f};
#pragma unroll
  for (int tm = 0; tm < 4; ++tm)
#pragma unroll
    for (int j = 0; j < 4; ++j) {
      int m = tm * 16 + g * 4 + j;
      int i2 = (m * 9363) >> 16;
      int j2 = m - i2 * 7;
      int rh = (wh < 7) ? 0 : (i2 < 4 ? 1 : 2);
      int rw = (ww < 7) ? 0 : (j2 < 4 ? 1 : 2);
      int Lm = rh * 3 + rw;
#pragma unroll
      for (int tn = 0; tn < 4; ++tn) {
        float s = acc[tm][tn][j] + lrow[m * 64 + tn * 16 + c];
        s = fmaxf(s, 0.f);
        if (Lm != Ln[tn]) s = 0.f;
        acc[tm][tn][j] = s;
        colmax[tn] = fmaxf(colmax[tn], s);
      }
    }
#pragma unroll
  for (int tn = 0; tn < 4; ++tn) {
    colmax[tn] = fmaxf(colmax[tn], __shfl_xor(colmax[tn], 16));
    colmax[tn] = fmaxf(colmax[tn], __shfl_xor(colmax[tn], 32));
  }
  float colsum[4] = {0.f, 0.f, 0.f, 0.f};
#pragma unroll
  for (int tm = 0; tm < 4; ++tm)
#pragma unroll
    for (int j = 0; j < 4; ++j) {
      int m = tm * 16 + g * 4 + j;
      bool mvalid = (m < NWT);
#pragma unroll
      for (int tn = 0; tn < 4; ++tn) {
        float e = mvalid ? __expf(acc[tm][tn][j] - colmax[tn]) : 0.f;
        acc[tm][tn][j] = e;
        colsum[tn] += e;
      }
    }
#pragma unroll
  for (int tn = 0; tn < 4; ++tn) {
    colsum[tn] += __shfl_xor(colsum[tn], 16);
    colsum[tn] += __shfl_xor(colsum[tn], 32);
    colsum[tn] = 1.f / colsum[tn];
  }

#pragma unroll
  for (int tn = 0; tn < 4; ++tn) {
    int n = tn * 16 + c;
#pragma unroll
    for (int tm = 0; tm < 4; ++tm) {
      float r = colsum[tn];
      *(uint2*)&Pw[n * 72 + tm * 16 + g * 4] =
          make_uint2(f2b2(acc[tm][tn][0] * r, acc[tm][tn][1] * r),
                     f2b2(acc[tm][tn][2] * r, acc[tm][tn][3] * r));
    }
  }

  f32x4 oacc[4][2] = {};
#pragma unroll
  for (int kcc = 0; kcc < 2; ++kcc) {
    bf16x8 pf[4];
#pragma unroll
    for (int tr = 0; tr < 4; ++tr)
      pf[tr] = *(const bf16x8*)&Pw[(tr * 16 + c) * 72 + kcc * 32 + g * 8];
#pragma unroll
    for (int tr = 0; tr < 4; ++tr)
#pragma unroll
      for (int td = 0; td < 2; ++td)
        oacc[tr][td] = __builtin_amdgcn_mfma_f32_16x16x32_bf16(pf[tr], vf[kcc][td], oacc[tr][td], 0, 0, 0);
  }

#pragma unroll
  for (int tr = 0; tr < 4; ++tr)
#pragma unroll
    for (int j = 0; j < 4; ++j) {
      int n = tr * 16 + g * 4 + j;
      if (n < NWT) {
#pragma unroll
        for (int td = 0; td < 2; ++td) {
          int d = td * 16 + c;
          out[((size_t)(win * NWT + n)) * CC + head * HDIM + d] =
              f2b(fmaxf(oacc[tr][td][j], 0.f));
        }
      }
    }
}

// ---------------- launch
extern "C" void kernel_launch(void* const* d_in, const int* in_sizes, int n_in,
                              void* d_out, int out_size, void* d_ws, size_t ws_size,
                              hipStream_t stream) {
  const float* x      = (const float*)d_in[0];
  const float* gamma1 = (const float*)d_in[1];
  const float* beta1  = (const float*)d_in[2];
  const float* w_qkv  = (const float*)d_in[3];
  const float* b_qkv  = (const float*)d_in[4];
  const float* rpb    = (const float*)d_in[5];
  const float* w_proj = (const float*)d_in[6];
  const float* b_proj = (const float*)d_in[7];
  const float* gamma2 = (const float*)d_in[8];
  const float* beta2  = (const float*)d_in[9];
  const float* w_fc1  = (const float*)d_in[10];
  const float* b_fc1  = (const float*)d_in[11];
  const float* w_fc2  = (const float*)d_in[12];
  const float* b_fc2  = (const float*)d_in[13];
  float* out = (float*)d_out;

  char* ws = (char*)d_ws;
  size_t off = 0;
  auto alloc = [&](size_t bytes) { void* p = ws + off; off = (off + bytes + 255) & ~(size_t)255; return p; };

  u16* wqkvT = (u16*)alloc(768 * 256 * 2);
  u16* wprojT = (u16*)alloc(256 * 256 * 2);
  u16* wfc1T = (u16*)alloc(1024 * 256 * 2);
  u16* wfc2T = (u16*)alloc(256 * 1024 * 2);
  float* lut = (float*)alloc(8 * 64 * 64 * 4);
  // region2 (51.4MB): xw -> attn_out   (strictly sequential lifetimes)
  u16* region2 = (u16*)alloc((size_t)NTOK * CC * 2);
  // region1 (154.2MB): q|k|v  ->  x2 (bf16 51.4MB, windowed) + xn2 (bf16 51.4MB)
  char* region1 = (char*)alloc((size_t)3 * NTOK * CC * 2);

  u16* xw = region2;
  u16* qb = (u16*)region1;
  u16* kb = qb + (size_t)NTOK * CC;
  u16* vb = kb + (size_t)NTOK * CC;
  u16* attn_out = region2;
  u16* x2 = (u16*)region1;
  u16* xn2 = x2 + (size_t)NTOK * CC;

  if (ws_size < off) return;

  prep_k<<<3200, 256, 0, stream>>>(w_qkv, w_proj, w_fc1, w_fc2, rpb,
                                   wqkvT, wprojT, wfc1T, wfc2T, lut);

  // LN1 + shift + partition
  ln_k<<<NTOK / 4, 256, 0, stream>>>(x, gamma1, beta1, xw);

  // QKV GEMM: M=100352, N=768, K=256
  gemm_k<EPI_QKV, 4><<<dim3(768 / BN, NTOK / BM), 256, 0, stream>>>(
      xw, wqkvT, b_qkv, (void*)qb, nullptr);

  // fused MFMA window attention
  attn_mfma_k<<<NWIN * NHEAD / 4, 256, 0, stream>>>(qb, kb, vb, lut, attn_out);

  // PROJ (128x256 tile) + reverse-shift residual + fused LN2 (windowed bf16 out)
  gemm_ln_k<<<NTOK / 128, 512, 0, stream>>>(
      attn_out, wprojT, b_proj, x, gamma2, beta2, x2, xn2);

  // fused MLP (r17 structure + fast GELU): single dispatch, h in LDS only
  mlp_fused_k<<<NTOK / 64, 512, 0, stream>>>(
      xn2, wfc1T, wfc2T, b_fc1, b_fc2, x2, out);
}

// Round 20
// 435.921 us; speedup vs baseline: 1.1275x; 1.0537x over previous
//
#include <hip/hip_runtime.h>
#include <stdint.h>

typedef unsigned short u16;
typedef short bf16x8 __attribute__((ext_vector_type(8)));
typedef float f32x4 __attribute__((ext_vector_type(4)));

#define NTOK 100352      // B*H*W tokens
#define NWIN 2048        // B * 64 windows
#define CC 256
#define NHEAD 8
#define HDIM 32
#define NWT 49           // tokens per window
#define MLPD 1024
#define ATT_SCALE 0.17677669529663687f  // 32^-0.5

__device__ __forceinline__ u16 f2b(float f) {
  union { float f; uint32_t u; } c; c.f = f;
  return (u16)((c.u + 0x7fffu + ((c.u >> 16) & 1u)) >> 16);
}
__device__ __forceinline__ float b2f(u16 h) {
  union { uint32_t u; float f; } c; c.u = ((uint32_t)h) << 16;
  return c.f;
}
// packed f32x2 -> bf16x2 (RNE), 1 VALU op
__device__ __forceinline__ uint32_t f2b2(float lo, float hi) {
  uint32_t r;
  asm("v_cvt_pk_bf16_f32 %0, %1, %2" : "=v"(r) : "v"(lo), "v"(hi));
  return r;
}

__device__ __forceinline__ void gload_lds16(const void* g, void* l) {
  __builtin_amdgcn_global_load_lds((const __attribute__((address_space(1))) void*)g,
                                   (__attribute__((address_space(3))) void*)l, 16, 0, 0);
}

// ---------------- prep: all weight transposes + bias LUT in ONE dispatch
__global__ __launch_bounds__(256)
void prep_k(const float* __restrict__ wqkv, const float* __restrict__ wproj,
            const float* __restrict__ wfc1, const float* __restrict__ wfc2,
            const float* __restrict__ rpb,
            u16* __restrict__ qkvT, u16* __restrict__ projT,
            u16* __restrict__ fc1T, u16* __restrict__ fc2T, float* __restrict__ lut) {
  int i = blockIdx.x * 256 + threadIdx.x;
  if (i < 196608) {                     // wqkv: K=256, N=768
    int k = i / 768, n = i % 768;
    qkvT[(size_t)n * 256 + k] = f2b(wqkv[i]);
  } else if (i < 262144) {              // wproj: 256x256
    int j = i - 196608, k = j / 256, n = j % 256;
    projT[(size_t)n * 256 + k] = f2b(wproj[j]);
  } else if (i < 524288) {              // wfc1: K=256, N=1024
    int j = i - 262144, k = j / 1024, n = j % 1024;
    fc1T[(size_t)n * 256 + k] = f2b(wfc1[j]);
  } else if (i < 786432) {              // wfc2: K=1024, N=256
    int j = i - 524288, k = j / 256, n = j % 256;
    fc2T[(size_t)n * 1024 + k] = f2b(wfc2[j]);
  } else if (i < 819200) {              // bias LUT lut[h][m][n], 64x64 padded
    int j = i - 786432;
    int h = j >> 12, m = (j >> 6) & 63, n = j & 63;
    float v = 0.f;
    if (m < 49 && n < 49) {
      int i1 = n / 7, j1 = n % 7, i2 = m / 7, j2 = m % 7;
      v = rpb[((i1 - i2 + 6) * 13 + (j1 - j2 + 6)) * 8 + h];
    }
    lut[j] = v;
  }
}

// ---------------- LN1 + cyclic-shift + window-partition -> bf16 tokens
__global__ __launch_bounds__(256)
void ln_k(const float* __restrict__ x, const float* __restrict__ g,
          const float* __restrict__ be, u16* __restrict__ out) {
  int token = blockIdx.x * 4 + (threadIdx.x >> 6);
  int lane = threadIdx.x & 63;
  int win = token / 49, nn = token % 49;
  int b = win >> 6, wh = (win >> 3) & 7, ww = win & 7;
  int i = nn / 7, j = nn % 7;
  int h = wh * 7 + i + 3; if (h >= 56) h -= 56;
  int w = ww * 7 + j + 3; if (w >= 56) w -= 56;
  size_t src = ((size_t)((b * 56 + h) * 56 + w)) * CC;
  f32x4 v = *(const f32x4*)&x[src + lane * 4];
  float s1 = v[0] + v[1] + v[2] + v[3];
  float s2 = v[0]*v[0] + v[1]*v[1] + v[2]*v[2] + v[3]*v[3];
#pragma unroll
  for (int o = 32; o; o >>= 1) { s1 += __shfl_xor(s1, o); s2 += __shfl_xor(s2, o); }
  float mean = s1 * (1.f / 256.f);
  float var = s2 * (1.f / 256.f) - mean * mean;
  float rstd = rsqrtf(var + 1e-5f);
  f32x4 gv = *(const f32x4*)&g[lane * 4];
  f32x4 bv = *(const f32x4*)&be[lane * 4];
  float y0 = (v[0]-mean)*rstd*gv[0] + bv[0];
  float y1 = (v[1]-mean)*rstd*gv[1] + bv[1];
  float y2 = (v[2]-mean)*rstd*gv[2] + bv[2];
  float y3 = (v[3]-mean)*rstd*gv[3] + bv[3];
  *(uint2*)&out[(size_t)token * CC + lane * 4] = make_uint2(f2b2(y0, y1), f2b2(y2, y3));
}

// ---------------- GEMM (128x128, BK=64): A dbuf (32KB) + B single-buffer (16KB)
#define BM 128
#define BN 128
enum { EPI_QKV = 0 };

template<int EPI, int NKT>
__global__ __launch_bounds__(256)
void gemm_k(const u16* __restrict__ A, const u16* __restrict__ BT,
            const float* __restrict__ bias,
            void* __restrict__ p0, const void* __restrict__ p1) {
  constexpr int K = NKT * 64;
  __shared__ u16 aL[2][BM * 64];   // 32KB double-buffered
  __shared__ u16 bL[BN * 64];      // 16KB single (staged 1 tile ahead)
  const int tid = threadIdx.x;
  const int lane = tid & 63;
  const int wv = tid >> 6;
  const int wm = wv >> 1, wn = wv & 1;

  int bx = blockIdx.x, by = blockIdx.y;
  {
    int nwg = gridDim.x * gridDim.y;
    int lin = by * gridDim.x + bx;
    int q = nwg >> 3, r = nwg & 7;
    int xcd = lin & 7, idx = lin >> 3;
    int wg = (xcd < r ? xcd * (q + 1) : r * (q + 1) + (xcd - r) * q) + idx;
    bx = wg % gridDim.x;
    by = wg / gridDim.x;
  }
  const long m0 = (long)by * BM;
  const int n0 = bx * BN;

  f32x4 acc[4][4] = {};   // [n-tile][m-tile]
  const int r15 = lane & 15;
  const int g4 = lane >> 4;

  const u16* pA[4];
  const u16* pB[4];
  int lslot[4];
#pragma unroll
  for (int it = 0; it < 4; ++it) {
    int slot = tid + 256 * it;
    int row = slot >> 3, c8 = slot & 7;
    int cs = c8 ^ (row & 7);
    pA[it] = &A[(m0 + row) * K + cs * 8];
    pB[it] = &BT[(size_t)(n0 + row) * K + cs * 8];
    lslot[it] = slot * 8;
  }
  int aoff[2][4], boff[2][4];
#pragma unroll
  for (int kk = 0; kk < 2; ++kk)
#pragma unroll
    for (int m = 0; m < 4; ++m) {
      int rowa = wm * 64 + m * 16 + r15;
      aoff[kk][m] = rowa * 64 + (((kk * 4 + g4) ^ (rowa & 7)) << 3);
      int rowb = wn * 64 + m * 16 + r15;
      boff[kk][m] = rowb * 64 + (((kk * 4 + g4) ^ (rowb & 7)) << 3);
    }

  auto stageA = [&](int bufi) {
#pragma unroll
    for (int it = 0; it < 4; ++it) { gload_lds16(pA[it], &aL[bufi][lslot[it]]); pA[it] += 64; }
  };
  auto stageB = [&]() {
#pragma unroll
    for (int it = 0; it < 4; ++it) { gload_lds16(pB[it], &bL[lslot[it]]); pB[it] += 64; }
  };

  stageB();
  stageA(0);
  stageA(1);

  for (int t = 0; t < NKT; ++t) {
    if (t + 1 < NKT) asm volatile("s_waitcnt vmcnt(4)" ::: "memory");
    else             asm volatile("s_waitcnt vmcnt(0)" ::: "memory");
    __builtin_amdgcn_sched_barrier(0);
    __builtin_amdgcn_s_barrier();
    __builtin_amdgcn_sched_barrier(0);
    {
      const u16* ab = aL[t & 1];
#pragma unroll
      for (int kk = 0; kk < 2; ++kk) {
        bf16x8 af[4], bfr[4];
#pragma unroll
        for (int m = 0; m < 4; ++m) af[m] = *(const bf16x8*)&ab[aoff[kk][m]];
#pragma unroll
        for (int n = 0; n < 4; ++n) bfr[n] = *(const bf16x8*)&bL[boff[kk][n]];
#pragma unroll
        for (int n = 0; n < 4; ++n)
#pragma unroll
          for (int m = 0; m < 4; ++m)
            acc[n][m] = __builtin_amdgcn_mfma_f32_16x16x32_bf16(bfr[n], af[m], acc[n][m], 0, 0, 0);
      }
    }
    __builtin_amdgcn_sched_barrier(0);
    __builtin_amdgcn_s_barrier();
    __builtin_amdgcn_sched_barrier(0);
    if (t + 1 < NKT) stageB();
    if (t + 2 < NKT) stageA(t & 1);
  }

  // epilogue (C^T): QKV scatter (head-major), relu, q-scale
#pragma unroll
  for (int mt = 0; mt < 4; ++mt) {
    const int mrow = (int)m0 + wm * 64 + mt * 16 + r15;
    int win = mrow / 49, nn = mrow - win * 49;
#pragma unroll
    for (int nt = 0; nt < 4; ++nt) {
      const int col0 = n0 + wn * 64 + nt * 16 + g4 * 4;
      f32x4 bv = *(const f32x4*)&bias[col0];
      f32x4 v;
#pragma unroll
      for (int j = 0; j < 4; ++j) v[j] = acc[nt][mt][j] + bv[j];
      int s = col0 >> 8, head = (col0 >> 5) & 7, d0 = col0 & 31;
      float sc = (s == 0) ? ATT_SCALE : 1.f;
#pragma unroll
      for (int j = 0; j < 4; ++j) v[j] = fmaxf(v[j], 0.f) * sc;
      u16* dst = (u16*)p0 + (size_t)s * ((size_t)NTOK * CC);
      *(uint2*)&dst[(((size_t)(win * NHEAD + head)) * NWT + nn) * HDIM + d0] =
          make_uint2(f2b2(v[0], v[1]), f2b2(v[2], v[3]));
    }
  }
}

// ---------------- PROJ (128x256, BK=64, 512 thr) + residual + FUSED LN2
__global__ __launch_bounds__(512)
void gemm_ln_k(const u16* __restrict__ A, const u16* __restrict__ BT,
               const float* __restrict__ bias, const float* __restrict__ xres,
               const float* __restrict__ g2, const float* __restrict__ be2,
               u16* __restrict__ x2, u16* __restrict__ xn2) {
  constexpr int K = 256;
  constexpr int NKT = 4;
  __shared__ u16 aL[2][128 * 64];   // 32KB
  __shared__ u16 bL[256 * 64];      // 32KB single
  __shared__ float st[4 * 128 * 2]; // 4KB stats
  const int tid = threadIdx.x;
  const int lane = tid & 63;
  const int wv = tid >> 6;
  const int wm = wv >> 2;
  const int wn = wv & 3;
  const int r15 = lane & 15;
  const int g4 = lane >> 4;

  int by = blockIdx.x;
  {
    int nwg = gridDim.x;
    int q = nwg >> 3, r = nwg & 7;
    int xcd = by & 7, idx = by >> 3;
    by = (xcd < r ? xcd * (q + 1) : r * (q + 1) + (xcd - r) * q) + idx;
  }
  const long m0 = (long)by * 128;

  f32x4 acc[4][4] = {};

  const u16* pA[2];
  int la[2];
#pragma unroll
  for (int it = 0; it < 2; ++it) {
    int slot = tid + 512 * it;
    int row = slot >> 3, c8 = slot & 7;
    int cs = c8 ^ (row & 7);
    pA[it] = &A[(m0 + row) * K + cs * 8];
    la[it] = slot * 8;
  }
  const u16* pB[4];
  int lb[4];
#pragma unroll
  for (int it = 0; it < 4; ++it) {
    int slot = tid + 512 * it;
    int row = slot >> 3, c8 = slot & 7;
    int cs = c8 ^ (row & 7);
    pB[it] = &BT[(size_t)row * K + cs * 8];
    lb[it] = slot * 8;
  }
  int aoff[2][4], boff[2][4];
#pragma unroll
  for (int kk = 0; kk < 2; ++kk)
#pragma unroll
    for (int m = 0; m < 4; ++m) {
      int rowa = wm * 64 + m * 16 + r15;
      aoff[kk][m] = rowa * 64 + (((kk * 4 + g4) ^ (rowa & 7)) << 3);
      int rowb = wn * 64 + m * 16 + r15;
      boff[kk][m] = rowb * 64 + (((kk * 4 + g4) ^ (rowb & 7)) << 3);
    }

  auto stageA = [&](int bufi) {
#pragma unroll
    for (int it = 0; it < 2; ++it) { gload_lds16(pA[it], &aL[bufi][la[it]]); pA[it] += 64; }
  };
  auto stageB = [&]() {
#pragma unroll
    for (int it = 0; it < 4; ++it) { gload_lds16(pB[it], &bL[lb[it]]); pB[it] += 64; }
  };

  stageB();
  stageA(0);
  stageA(1);

  for (int t = 0; t < NKT; ++t) {
    if (t + 1 < NKT) asm volatile("s_waitcnt vmcnt(2)" ::: "memory");
    else             asm volatile("s_waitcnt vmcnt(0)" ::: "memory");
    __builtin_amdgcn_sched_barrier(0);
    __builtin_amdgcn_s_barrier();
    __builtin_amdgcn_sched_barrier(0);
    {
      const u16* ab = aL[t & 1];
#pragma unroll
      for (int kk = 0; kk < 2; ++kk) {
        bf16x8 af[4], bfr[4];
#pragma unroll
        for (int m = 0; m < 4; ++m) af[m] = *(const bf16x8*)&ab[aoff[kk][m]];
#pragma unroll
        for (int n = 0; n < 4; ++n) bfr[n] = *(const bf16x8*)&bL[boff[kk][n]];
#pragma unroll
        for (int n = 0; n < 4; ++n)
#pragma unroll
          for (int m = 0; m < 4; ++m)
            acc[n][m] = __builtin_amdgcn_mfma_f32_16x16x32_bf16(bfr[n], af[m], acc[n][m], 0, 0, 0);
      }
    }
    __builtin_amdgcn_sched_barrier(0);
    __builtin_amdgcn_s_barrier();
    __builtin_amdgcn_sched_barrier(0);
    if (t + 1 < NKT) stageB();
    if (t + 2 < NKT) stageA(t & 1);
  }

  // ---- epilogue: v = x[pix] + proj + bias; x2(bf16, windowed); LN -> xn2
  size_t pix[4];
  float s1[4] = {}, s2[4] = {};
#pragma unroll
  for (int mt = 0; mt < 4; ++mt) {
    const int mrow = (int)m0 + wm * 64 + mt * 16 + r15;
    int win = mrow / 49, nn = mrow - win * 49;
    int b = win >> 6, wh = (win >> 3) & 7, ww = win & 7;
    int i = nn / 7, jj = nn - i * 7;
    int h = wh * 7 + i + 3; if (h >= 56) h -= 56;
    int w = ww * 7 + jj + 3; if (w >= 56) w -= 56;
    pix[mt] = (size_t)((b * 56 + h) * 56 + w);
#pragma unroll
    for (int nt = 0; nt < 4; ++nt) {
      const int col0 = wn * 64 + nt * 16 + g4 * 4;
      f32x4 bv = *(const f32x4*)&bias[col0];
      f32x4 r = *(const f32x4*)&xres[pix[mt] * CC + col0];
      f32x4 v;
#pragma unroll
      for (int j = 0; j < 4; ++j) {
        v[j] = acc[nt][mt][j] + bv[j] + r[j];
        s1[mt] += v[j];
        s2[mt] += v[j] * v[j];
      }
      *(uint2*)&x2[(size_t)mrow * CC + col0] =
          make_uint2(f2b2(v[0], v[1]), f2b2(v[2], v[3]));
      acc[nt][mt] = v;
    }
    s1[mt] += __shfl_xor(s1[mt], 16);  s1[mt] += __shfl_xor(s1[mt], 32);
    s2[mt] += __shfl_xor(s2[mt], 16);  s2[mt] += __shfl_xor(s2[mt], 32);
    if (g4 == 0) {
      int wrow = wm * 64 + mt * 16 + r15;
      st[(wn * 128 + wrow) * 2 + 0] = s1[mt];
      st[(wn * 128 + wrow) * 2 + 1] = s2[mt];
    }
  }
  __syncthreads();
#pragma unroll
  for (int mt = 0; mt < 4; ++mt) {
    const int mrow = (int)m0 + wm * 64 + mt * 16 + r15;
    int wrow = wm * 64 + mt * 16 + r15;
    float t1 = 0.f, t2 = 0.f;
#pragma unroll
    for (int w2 = 0; w2 < 4; ++w2) {
      t1 += st[(w2 * 128 + wrow) * 2 + 0];
      t2 += st[(w2 * 128 + wrow) * 2 + 1];
    }
    float mean = t1 * (1.f / 256.f);
    float var = t2 * (1.f / 256.f) - mean * mean;
    float rstd = rsqrtf(var + 1e-5f);
#pragma unroll
    for (int nt = 0; nt < 4; ++nt) {
      const int col0 = wn * 64 + nt * 16 + g4 * 4;
      f32x4 gv = *(const f32x4*)&g2[col0];
      f32x4 bv = *(const f32x4*)&be2[col0];
      float y0 = (acc[nt][mt][0] - mean) * rstd * gv[0] + bv[0];
      float y1 = (acc[nt][mt][1] - mean) * rstd * gv[1] + bv[1];
      float y2 = (acc[nt][mt][2] - mean) * rstd * gv[2] + bv[2];
      float y3 = (acc[nt][mt][3] - mean) * rstd * gv[3] + bv[3];
      *(uint2*)&xn2[(size_t)mrow * CC + col0] = make_uint2(f2b2(y0, y1), f2b2(y2, y3));
    }
  }
}

// ---------------- FUSED MLP v3: BK=128 stage-1 (2 fat K-phases) + B2 dbuf
// (both kt issued pre-GELU) -> barriers/chunk 11 -> 7, 16 MFMA per phase.
// acc regs unchanged vs r17 (no spill risk). LDS 80KB -> 2 blocks/CU.
__global__ __launch_bounds__(512, 4)
void mlp_fused_k(const u16* __restrict__ xn, const u16* __restrict__ fc1T,
                 const u16* __restrict__ fc2T, const float* __restrict__ b1,
                 const float* __restrict__ b2v, const u16* __restrict__ x2,
                 float* __restrict__ outp) {
  __shared__ u16 lds[40960];           // 80KB
  u16* shA0 = lds;                     // [0,8192)      16KB  A buf0 (64x128)
  u16* shA1 = lds + 8192;              // [8192,16384)  16KB  A buf1
  u16* shB1 = lds + 16384;             // [16384,32768) 32KB  B1 (128x128)
  u16* shB2_0 = lds;                   // [0,16384)     32KB  B2 kt0 (aliases A)
  u16* shB2_1 = lds + 16384;           // [16384,32768) 32KB  B2 kt1 (aliases B1)
  u16* shH  = lds + 32768;             // [32768,40960) 16KB  h chunk (64x128)

  const int tid = threadIdx.x;
  const int lane = tid & 63;
  const int wv = tid >> 6;             // 8 waves
  const int wmw = wv >> 2;             // 0..1: 32-row half
  const int wnw = wv & 3;              // 0..3: col quarter
  const int r15 = lane & 15;
  const int g4 = lane >> 4;

  int by = blockIdx.x;
  {
    int nwg = gridDim.x;
    int q = nwg >> 3, r = nwg & 7;
    int xcd = by & 7, idx = by >> 3;
    by = (xcd < r ? xcd * (q + 1) : r * (q + 1) + (xcd - r) * q) + idx;
  }
  const long m0 = (long)by * 64;

  // ---- staging thread->slot maps (16-chunk rows: swizzle c16 ^ (row&15))
  // A: 64x128 (16KB/tile): 2 gloads/thread
  int laA[2];
  const u16* pAbase[2];
#pragma unroll
  for (int it = 0; it < 2; ++it) {
    int slot = tid + 512 * it;
    int row = slot >> 4, c16 = slot & 15;
    int cs = c16 ^ (row & 15);
    pAbase[it] = &xn[(m0 + row) * 256 + cs * 8];     // + t*128
    laA[it] = slot * 8;
  }
  // B1: 128x128 (32KB/tile): 4 gloads/thread
  int lb1[4];
  const u16* pB1base[4];
#pragma unroll
  for (int it = 0; it < 4; ++it) {
    int slot = tid + 512 * it;
    int row = slot >> 4, c16 = slot & 15;
    int cs = c16 ^ (row & 15);
    pB1base[it] = &fc1T[(size_t)row * 256 + cs * 8]; // + hc*128*256 + t*128
    lb1[it] = slot * 8;
  }
  // B2: 256x64 per kt (32KB): 4 gloads/thread (8-chunk rows: c8 ^ (row&7))
  int lb2[4];
  const u16* pB2base[4];
#pragma unroll
  for (int it = 0; it < 4; ++it) {
    int slot = tid + 512 * it;
    int row = slot >> 3, c8 = slot & 7;
    int cs = c8 ^ (row & 7);
    pB2base[it] = &fc2T[(size_t)row * 1024 + cs * 8]; // + hc*128 + kt*64
    lb2[it] = slot * 8;
  }

  // ---- hoisted read offsets
  // stage1 (BK=128, kk<4): A rows wmw*32+m*16+r15; B1 rows wnw*32+n*16+r15
  int a1off[4][2], b1off[4][2];
#pragma unroll
  for (int kk = 0; kk < 4; ++kk)
#pragma unroll
    for (int m = 0; m < 2; ++m) {
      int ra = wmw * 32 + m * 16 + r15;
      a1off[kk][m] = ra * 128 + (((kk * 4 + g4) ^ (ra & 15)) << 3);
      int rb = wnw * 32 + m * 16 + r15;
      b1off[kk][m] = rb * 128 + (((kk * 4 + g4) ^ (rb & 15)) << 3);
    }
  // stage2: B2 rows wnw*64+n*16+r15 (n<4), 8-chunk swizzle
  int b2off[2][4];
#pragma unroll
  for (int kk = 0; kk < 2; ++kk)
#pragma unroll
    for (int n = 0; n < 4; ++n) {
      int rb = wnw * 64 + n * 16 + r15;
      b2off[kk][n] = rb * 64 + (((kk * 4 + g4) ^ (rb & 7)) << 3);
    }

  f32x4 oacc[4][2] = {};   // [nt(out col)][mt(row)]

  for (int hc = 0; hc < 8; ++hc) {
    // ======== stage 1: acc1 = xn @ fc1T[hc]  (M64 x N128, K=256, BK=128) ====
    const size_t b1chunk = (size_t)hc * 128 * 256;
    // prologue: B1(t0)[4] + A(t0)[2] + A(t1)[2] = 8 outstanding
    gload_lds16(pB1base[0] + b1chunk, &shB1[lb1[0]]);
    gload_lds16(pB1base[1] + b1chunk, &shB1[lb1[1]]);
    gload_lds16(pB1base[2] + b1chunk, &shB1[lb1[2]]);
    gload_lds16(pB1base[3] + b1chunk, &shB1[lb1[3]]);
    gload_lds16(pAbase[0],       &shA0[laA[0]]);
    gload_lds16(pAbase[1],       &shA0[laA[1]]);
    gload_lds16(pAbase[0] + 128, &shA1[laA[0]]);
    gload_lds16(pAbase[1] + 128, &shA1[laA[1]]);

    f32x4 acc1[2][2] = {};   // [nt][mt]
#pragma unroll
    for (int t = 0; t < 2; ++t) {
      if (t == 0) asm volatile("s_waitcnt vmcnt(2)" ::: "memory");  // A(t1) in flight
      else        asm volatile("s_waitcnt vmcnt(0)" ::: "memory");
      __builtin_amdgcn_sched_barrier(0);
      __builtin_amdgcn_s_barrier();
      __builtin_amdgcn_sched_barrier(0);
      {
        const u16* ab = t ? shA1 : shA0;
#pragma unroll
        for (int kk = 0; kk < 4; ++kk) {
          bf16x8 af[2], bfr[2];
#pragma unroll
          for (int m = 0; m < 2; ++m) af[m] = *(const bf16x8*)&ab[a1off[kk][m]];
#pragma unroll
          for (int n = 0; n < 2; ++n) bfr[n] = *(const bf16x8*)&shB1[b1off[kk][n]];
#pragma unroll
          for (int n = 0; n < 2; ++n)
#pragma unroll
            for (int m = 0; m < 2; ++m)
              acc1[n][m] = __builtin_amdgcn_mfma_f32_16x16x32_bf16(bfr[n], af[m], acc1[n][m], 0, 0, 0);
        }
      }
      __builtin_amdgcn_sched_barrier(0);
      __builtin_amdgcn_s_barrier();
      __builtin_amdgcn_sched_barrier(0);
      if (t == 0) {   // B1(t1) into the single buffer (all waves done reading)
        gload_lds16(pB1base[0] + b1chunk + 128, &shB1[lb1[0]]);
        gload_lds16(pB1base[1] + b1chunk + 128, &shB1[lb1[1]]);
        gload_lds16(pB1base[2] + b1chunk + 128, &shB1[lb1[2]]);
        gload_lds16(pB1base[3] + b1chunk + 128, &shB1[lb1[3]]);
      }
    }
    // A+B1 region free (post-t1 barrier). Issue BOTH B2 kt tiles (dbuf).
    gload_lds16(pB2base[0] + hc * 128, &shB2_0[lb2[0]]);
    gload_lds16(pB2base[1] + hc * 128, &shB2_0[lb2[1]]);
    gload_lds16(pB2base[2] + hc * 128, &shB2_0[lb2[2]]);
    gload_lds16(pB2base[3] + hc * 128, &shB2_0[lb2[3]]);
    gload_lds16(pB2base[0] + hc * 128 + 64, &shB2_1[lb2[0]]);
    gload_lds16(pB2base[1] + hc * 128 + 64, &shB2_1[lb2[1]]);
    gload_lds16(pB2base[2] + hc * 128 + 64, &shB2_1[lb2[2]]);
    gload_lds16(pB2base[3] + hc * 128 + 64, &shB2_1[lb2[3]]);

    // fast sigmoid-GELU -> h chunk in LDS (C^T layout; 16-chunk XOR swizzle)
#pragma unroll
    for (int mt = 0; mt < 2; ++mt) {
      const int hrow = wmw * 32 + mt * 16 + r15;
#pragma unroll
      for (int nt = 0; nt < 2; ++nt) {
        const int col0 = wnw * 32 + nt * 16 + g4 * 4;
        f32x4 bv = *(const f32x4*)&b1[hc * 128 + col0];
        f32x4 v;
#pragma unroll
        for (int j = 0; j < 4; ++j) {
          float u = acc1[nt][mt][j] + bv[j];
          float u2 = u * u;
          float tt = u * fmaf(0.044715f, u2, 1.f);
          float e = exp2f(tt * -2.3022029f);        // e^{-2*0.79788456*tt}
          v[j] = u * __builtin_amdgcn_rcpf(1.f + e);
        }
        int hidx = hrow * 128 + (((col0 >> 3) ^ (hrow & 15)) << 3) + (col0 & 7);
        *(uint2*)&shH[hidx] = make_uint2(f2b2(v[0], v[1]), f2b2(v[2], v[3]));
      }
    }
    asm volatile("s_waitcnt lgkmcnt(0)" ::: "memory");
    __builtin_amdgcn_sched_barrier(0);
    asm volatile("s_waitcnt vmcnt(4)" ::: "memory");   // B2 kt0 landed, kt1 in flight
    __builtin_amdgcn_sched_barrier(0);
    __builtin_amdgcn_s_barrier();                      // h + B2 kt0 visible
    __builtin_amdgcn_sched_barrier(0);

    // ======== stage 2: oacc += h @ fc2T[:, hc*128..)  (M64 x N256, K=128) ====
#pragma unroll
    for (int kt = 0; kt < 2; ++kt) {
      const u16* bb = kt ? shB2_1 : shB2_0;
#pragma unroll
      for (int kk = 0; kk < 2; ++kk) {
        bf16x8 af[2], bfr[4];
#pragma unroll
        for (int m = 0; m < 2; ++m) {
          int hrow = wmw * 32 + m * 16 + r15;
          int kchunk = kt * 8 + kk * 4 + g4;
          af[m] = *(const bf16x8*)&shH[hrow * 128 + ((kchunk ^ (hrow & 15)) << 3)];
        }
#pragma unroll
        for (int n = 0; n < 4; ++n) bfr[n] = *(const bf16x8*)&bb[b2off[kk][n]];
#pragma unroll
        for (int n = 0; n < 4; ++n)
#pragma unroll
          for (int m = 0; m < 2; ++m)
            oacc[n][m] = __builtin_amdgcn_mfma_f32_16x16x32_bf16(bfr[n], af[m], oacc[n][m], 0, 0, 0);
      }
      if (kt == 0) {
        asm volatile("s_waitcnt vmcnt(0)" ::: "memory");  // kt1's loads drained
        __builtin_amdgcn_sched_barrier(0);
        __builtin_amdgcn_s_barrier();                     // buf1 visible to all
        __builtin_amdgcn_sched_barrier(0);
      } else {
        __builtin_amdgcn_sched_barrier(0);
        __builtin_amdgcn_s_barrier();   // frees whole region for next chunk
        __builtin_amdgcn_sched_barrier(0);
      }
    }
  }

  // ======== epilogue: out = x2 + oacc + b2, reverse-shift scatter ========
#pragma unroll
  for (int mt = 0; mt < 2; ++mt) {
    const int mrow = (int)m0 + wmw * 32 + mt * 16 + r15;
    int win = mrow / 49, nn = mrow - win * 49;
    int b = win >> 6, wh = (win >> 3) & 7, ww = win & 7;
    int i = nn / 7, jj = nn - i * 7;
    int h = wh * 7 + i + 3; if (h >= 56) h -= 56;
    int w = ww * 7 + jj + 3; if (w >= 56) w -= 56;
    size_t pix = (size_t)((b * 56 + h) * 56 + w);
#pragma unroll
    for (int nt = 0; nt < 4; ++nt) {
      const int col0 = wnw * 64 + nt * 16 + g4 * 4;
      f32x4 bv = *(const f32x4*)&b2v[col0];
      f32x4 v;
#pragma unroll
      for (int j = 0; j < 4; ++j) v[j] = oacc[nt][mt][j] + bv[j];
      uint2 rb = *(const uint2*)&x2[(size_t)mrow * CC + col0];
      v[0] += b2f((u16)(rb.x & 0xffffu));
      v[1] += b2f((u16)(rb.x >> 16));
      v[2] += b2f((u16)(rb.y & 0xffffu));
      v[3] += b2f((u16)(rb.y >> 16));
      *(f32x4*)&outp[pix * CC + col0] = v;
    }
  }
}

// ---------------- MFMA window attention: 1 wave = 1 (window, head), 4 waves/block
__global__ __launch_bounds__(256)
void attn_mfma_k(const u16* __restrict__ q, const u16* __restrict__ k2,
                 const u16* __restrict__ v2, const float* __restrict__ lut,
                 u16* __restrict__ out) {
  __shared__ u16 P_lds[4][64 * 72];
  const int tid = threadIdx.x;
  const int wv = tid >> 6;
  const int lane = tid & 63;
  const int c = lane & 15;
  const int g = lane >> 4;
  const int blk = blockIdx.x * 4 + wv;
  const int head = blk & 7;
  const int win = blk >> 3;
  const int wimg = win & 63;
  const int wh = wimg >> 3, ww = wimg & 7;
  const size_t base = (size_t)blk * (NWT * HDIM);
  u16* Pw = P_lds[wv];

  bf16x8 kf[4], qf[4];
#pragma unroll
  for (int t = 0; t < 4; ++t) {
    kf[t] = *(const bf16x8*)&k2[base + (size_t)(t * 16 + c) * HDIM + g * 8];
    qf[t] = *(const bf16x8*)&q [base + (size_t)(t * 16 + c) * HDIM + g * 8];
  }
  bf16x8 vf[2][2];
#pragma unroll
  for (int kcc = 0; kcc < 2; ++kcc)
#pragma unroll
    for (int td = 0; td < 2; ++td)
#pragma unroll
      for (int jj = 0; jj < 8; ++jj) {
        int m = kcc * 32 + g * 8 + jj;
        m = m < 49 ? m : 48;
        vf[kcc][td][jj] = (short)v2[base + (size_t)m * HDIM + td * 16 + c];
      }

  f32x4 acc[4][4] = {};
#pragma unroll
  for (int tm = 0; tm < 4; ++tm)
#pragma unroll
    for (int tn = 0; tn < 4; ++tn)
      acc[tm][tn] = __builtin_amdgcn_mfma_f32_16x16x32_bf16(kf[tm], qf[tn], acc[tm][tn], 0, 0, 0);

  const float* lrow = &lut[(size_t)head * 64 * 64];
  int Ln[4];
#pragma unroll
  for (int tn = 0; tn < 4; ++tn) {
    int n = tn * 16 + c;
    int i1 = (n * 9363) >> 16;
    int j1 = n - i1 * 7;
    int rh = (wh < 7) ? 0 : (i1 < 4 ? 1 : 2);
    int rw = (ww < 7) ? 0 : (j1 < 4 ? 1 : 2);
    Ln[tn] = rh * 3 + rw;
  }
  float colmax[4] = {0.f, 0.f, 0.f, 0.f};
#pragma unroll
  for (int tm = 0; tm < 4; ++tm)
#pragma unroll
    for (int j = 0; j < 4; ++j) {
      int m = tm * 16 + g * 4 + j;
      int i2 = (m * 9363) >> 16;
      int j2 = m - i2 * 7;
      int rh = (wh < 7) ? 0 : (i2 < 4 ? 1 : 2);
      int rw = (ww < 7) ? 0 : (j2 < 4 ? 1 : 2);
      int Lm = rh * 3 + rw;
#pragma unroll
      for (int tn = 0; tn < 4; ++tn) {
        float s = acc[tm][tn][j] + lrow[m * 64 + tn * 16 + c];
        s = fmaxf(s, 0.f);
        if (Lm != Ln[tn]) s = 0.f;
        acc[tm][tn][j] = s;
        colmax[tn] = fmaxf(colmax[tn], s);
      }
    }
#pragma unroll
  for (int tn = 0; tn < 4; ++tn) {
    colmax[tn] = fmaxf(colmax[tn], __shfl_xor(colmax[tn], 16));
    colmax[tn] = fmaxf(colmax[tn], __shfl_xor(colmax[tn], 32));
  }
  float colsum[4] = {0.f, 0.f, 0.f, 0.f};
#pragma unroll
  for (int tm = 0; tm < 4; ++tm)
#pragma unroll
    for (int j = 0; j < 4; ++j) {
      int m = tm * 16 + g * 4 + j;
      bool mvalid = (m < NWT);
#pragma unroll
      for (int tn = 0; tn < 4; ++tn) {
        float e = mvalid ? __expf(acc[tm][tn][j] - colmax[tn]) : 0.f;
        acc[tm][tn][j] = e;
        colsum[tn] += e;
      }
    }
#pragma unroll
  for (int tn = 0; tn < 4; ++tn) {
    colsum[tn] += __shfl_xor(colsum[tn], 16);
    colsum[tn] += __shfl_xor(colsum[tn], 32);
    colsum[tn] = 1.f / colsum[tn];
  }

#pragma unroll
  for (int tn = 0; tn < 4; ++tn) {
    int n = tn * 16 + c;
#pragma unroll
    for (int tm = 0; tm < 4; ++tm) {
      float r = colsum[tn];
      *(uint2*)&Pw[n * 72 + tm * 16 + g * 4] =
          make_uint2(f2b2(acc[tm][tn][0] * r, acc[tm][tn][1] * r),
                     f2b2(acc[tm][tn][2] * r, acc[tm][tn][3] * r));
    }
  }

  f32x4 oacc[4][2] = {};
#pragma unroll
  for (int kcc = 0; kcc < 2; ++kcc) {
    bf16x8 pf[4];
#pragma unroll
    for (int tr = 0; tr < 4; ++tr)
      pf[tr] = *(const bf16x8*)&Pw[(tr * 16 + c) * 72 + kcc * 32 + g * 8];
#pragma unroll
    for (int tr = 0; tr < 4; ++tr)
#pragma unroll
      for (int td = 0; td < 2; ++td)
        oacc[tr][td] = __builtin_amdgcn_mfma_f32_16x16x32_bf16(pf[tr], vf[kcc][td], oacc[tr][td], 0, 0, 0);
  }

#pragma unroll
  for (int tr = 0; tr < 4; ++tr)
#pragma unroll
    for (int j = 0; j < 4; ++j) {
      int n = tr * 16 + g * 4 + j;
      if (n < NWT) {
#pragma unroll
        for (int td = 0; td < 2; ++td) {
          int d = td * 16 + c;
          out[((size_t)(win * NWT + n)) * CC + head * HDIM + d] =
              f2b(fmaxf(oacc[tr][td][j], 0.f));
        }
      }
    }
}

// ---------------- launch
extern "C" void kernel_launch(void* const* d_in, const int* in_sizes, int n_in,
                              void* d_out, int out_size, void* d_ws, size_t ws_size,
                              hipStream_t stream) {
  const float* x      = (const float*)d_in[0];
  const float* gamma1 = (const float*)d_in[1];
  const float* beta1  = (const float*)d_in[2];
  const float* w_qkv  = (const float*)d_in[3];
  const float* b_qkv  = (const float*)d_in[4];
  const float* rpb    = (const float*)d_in[5];
  const float* w_proj = (const float*)d_in[6];
  const float* b_proj = (const float*)d_in[7];
  const float* gamma2 = (const float*)d_in[8];
  const float* beta2  = (const float*)d_in[9];
  const float* w_fc1  = (const float*)d_in[10];
  const float* b_fc1  = (const float*)d_in[11];
  const float* w_fc2  = (const float*)d_in[12];
  const float* b_fc2  = (const float*)d_in[13];
  float* out = (float*)d_out;

  char* ws = (char*)d_ws;
  size_t off = 0;
  auto alloc = [&](size_t bytes) { void* p = ws + off; off = (off + bytes + 255) & ~(size_t)255; return p; };

  u16* wqkvT = (u16*)alloc(768 * 256 * 2);
  u16* wprojT = (u16*)alloc(256 * 256 * 2);
  u16* wfc1T = (u16*)alloc(1024 * 256 * 2);
  u16* wfc2T = (u16*)alloc(256 * 1024 * 2);
  float* lut = (float*)alloc(8 * 64 * 64 * 4);
  // region2 (51.4MB): xw -> attn_out   (strictly sequential lifetimes)
  u16* region2 = (u16*)alloc((size_t)NTOK * CC * 2);
  // region1 (154.2MB): q|k|v  ->  x2 (bf16 51.4MB, windowed) + xn2 (bf16 51.4MB)
  char* region1 = (char*)alloc((size_t)3 * NTOK * CC * 2);

  u16* xw = region2;
  u16* qb = (u16*)region1;
  u16* kb = qb + (size_t)NTOK * CC;
  u16* vb = kb + (size_t)NTOK * CC;
  u16* attn_out = region2;
  u16* x2 = (u16*)region1;
  u16* xn2 = x2 + (size_t)NTOK * CC;

  if (ws_size < off) return;

  prep_k<<<3200, 256, 0, stream>>>(w_qkv, w_proj, w_fc1, w_fc2, rpb,
                                   wqkvT, wprojT, wfc1T, wfc2T, lut);

  // LN1 + shift + partition
  ln_k<<<NTOK / 4, 256, 0, stream>>>(x, gamma1, beta1, xw);

  // QKV GEMM: M=100352, N=768, K=256
  gemm_k<EPI_QKV, 4><<<dim3(768 / BN, NTOK / BM), 256, 0, stream>>>(
      xw, wqkvT, b_qkv, (void*)qb, nullptr);

  // fused MFMA window attention
  attn_mfma_k<<<NWIN * NHEAD / 4, 256, 0, stream>>>(qb, kb, vb, lut, attn_out);

  // PROJ (128x256 tile) + reverse-shift residual + fused LN2 (windowed bf16 out)
  gemm_ln_k<<<NTOK / 128, 512, 0, stream>>>(
      attn_out, wprojT, b_proj, x, gamma2, beta2, x2, xn2);

  // fused MLP v3 (BK=128 stage-1 + B2 dbuf): single dispatch, h in LDS only
  mlp_fused_k<<<NTOK / 64, 512, 0, stream>>>(
      xn2, wfc1T, wfc2T, b_fc1, b_fc2, x2, out);
}